// Round 5
// baseline (1705.867 us; speedup 1.0000x reference)
//
#include <hip/hip_runtime.h>
#include <hip/hip_fp16.h>
#include <math.h>

#define SD 10
#define BB 8                  // bucket bits (nodes-per-bucket = 256)
#define BSZ 256               // nodes per bucket
#define MAXNB 1024            // N <= 1024*256 = 262144 (and N < 2^18 gate)
#define EB 512                // edge-chunk blocks (pass-1 grid)
#define CTHR 1024             // threads for pass 1
#define NBIN_MAX 32           // coarse bins (nto >> 13), 8192 nodes/bin
#define SLICES 32             // pass-2 source slices per bin
#define SW (EB / SLICES)      // 16 source blocks per slice

typedef unsigned uvec4 __attribute__((ext_vector_type(4)));
union U32H2 { unsigned u; __half2 h; };

__device__ __forceinline__ float tanh_fast(float x) {
    float e = __expf(2.0f * x);
    float r = __builtin_amdgcn_rcpf(1.0f + e);
    return 1.0f - 2.0f * r;
}

__device__ __forceinline__ float softplus_f(float x) {
    return fmaxf(x, 0.0f) + log1pf(expf(-fabsf(x)));
}

// ===================== prep =====================

__global__ __launch_bounds__(256) void coords4_kernel(
    const float* __restrict__ coords, float4* __restrict__ coords4, int N)
{
    int n = blockIdx.x * blockDim.x + threadIdx.x;
    if (n >= N) return;
    float4 c;
    c.x = coords[n * 3 + 0];
    c.y = coords[n * 3 + 1];
    c.z = coords[n * 3 + 2];
    c.w = 0.0f;
    coords4[n] = c;
}

// ===================== build: 2-pass radix partition =====================
// Invariant that rounds 0-4 kept violating: a scatter's live-partial-line
// footprint = resident_blocks_per_XCD x targets x 128B must fit in 4MB L2.
// Pass 1 scatters to <=32 coarse bins (footprint ~256KB/XCD); pass 2 scatters
// each bin to its <=32 final buckets (footprint ~256KB/XCD). Never 782 targets.

// Pass 1: block b histograms its chunk (fine buckets -> gcnt column), then
// emits records into its chunk range ordered by coarse bin. Also emits
// s1addr[bin][b] = absolute start of segment (bin,b). Record: p.w = fine bucket.
__global__ __launch_bounds__(CTHR) void pass1_kernel(
    const float4* __restrict__ coords4,
    const float* __restrict__ elen,
    const float* __restrict__ evec,
    const int* __restrict__ nfrom,
    const int* __restrict__ nto,
    unsigned* __restrict__ gcnt,
    unsigned* __restrict__ s1addr,
    uvec4* __restrict__ payA,
    int E, int NB)
{
    __shared__ unsigned hfine[MAXNB];     // 4 KB
    __shared__ unsigned hbin[NBIN_MAX];
    __shared__ unsigned curbin[NBIN_MAX];
    int b = blockIdx.x, t = threadIdx.x;
    long long ebeg = (long long)E * b / EB;
    long long eend = (long long)E * (b + 1) / EB;
    int NBIN = (NB + 31) >> 5;

    for (int i = t; i < NB; i += CTHR) hfine[i] = 0;
    __syncthreads();
    for (long long e = ebeg + t; e < eend; e += CTHR)
        atomicAdd(&hfine[((unsigned)nto[e]) >> BB], 1u);
    __syncthreads();
    if (t < NBIN_MAX) {
        unsigned s = 0;
#pragma unroll
        for (int q = 0; q < 32; q++) {
            int k = t * 32 + q;
            if (k < NB) s += hfine[k];
        }
        hbin[t] = s;
    }
    __syncthreads();
    if (t == 0) {                          // trivial serial scan over <=32 bins
        unsigned run = (unsigned)ebeg;
        for (int q = 0; q < NBIN; q++) { unsigned c = hbin[q]; curbin[q] = run; run += c; }
    }
    __syncthreads();
    for (int k = t; k < NB; k += CTHR) gcnt[(size_t)k * EB + b] = hfine[k];
    if (t < NBIN) s1addr[t * EB + b] = curbin[t];
    __syncthreads();

    for (long long e = ebeg + t; e < eend; e += CTHR) {
        int nf = nfrom[e];
        int nt = nto[e];
        unsigned bin = ((unsigned)nt) >> (BB + 5);
        unsigned pos = atomicAdd(&curbin[bin], 1u);

        float4 cf = coords4[nf];
        float4 ct = coords4[nt];
        float ev0 = evec[e * 3 + 0], ev1 = evec[e * 3 + 1], ev2 = evec[e * 3 + 2];

        float g0 = elen[e];
        float g1 = fabsf(cf.x) + fabsf(cf.y) + fabsf(cf.z);
        float g2 = cf.x * ct.x + cf.y * ct.y + cf.z * ct.z;
        float g3 = cf.x * ev0 + cf.y * ev1 + cf.z * ev2;

        U32H2 c01, c23;
        c01.h = __floats2half2_rn(g0, g1);
        c23.h = __floats2half2_rn(g2, g3);
        uvec4 p;
        p.x = (unsigned)nf | (((unsigned)nt & (BSZ - 1)) << 18);
        p.y = c01.u;
        p.z = c23.u;
        p.w = ((unsigned)nt) >> BB;        // fine bucket, consumed by pass 2
        payA[pos] = p;
    }
}

// Row sums of gcnt -> bsum[k] (bucket totals). EB == 512, 256 threads: 2 each.
__global__ __launch_bounds__(256) void rowsum_kernel(
    const unsigned* __restrict__ gcnt, unsigned* __restrict__ bsum)
{
    __shared__ unsigned red[256];
    int k = blockIdx.x, t = threadIdx.x;
    red[t] = gcnt[(size_t)k * EB + t] + gcnt[(size_t)k * EB + t + 256];
    __syncthreads();
    for (int d = 128; d > 0; d >>= 1) {
        if (t < d) red[t] += red[t + d];
        __syncthreads();
    }
    if (t == 0) bsum[k] = red[0];
}

// Exclusive scan of bsum (NB <= 1024) -> bstart[0..NB]. Single block.
__global__ __launch_bounds__(256) void bscan_kernel(
    const unsigned* __restrict__ bsum, unsigned* __restrict__ bstart, int NB, int E)
{
    __shared__ unsigned lds[256];
    int t = threadIdx.x;
    unsigned v[4], s = 0;
#pragma unroll
    for (int c = 0; c < 4; c++) {
        int i = t * 4 + c;
        v[c] = (i < NB) ? bsum[i] : 0u;
        s += v[c];
    }
    lds[t] = s;
    __syncthreads();
    for (int d = 1; d < 256; d <<= 1) {
        unsigned x = (t >= d) ? lds[t - d] : 0u;
        __syncthreads();
        lds[t] += x;
        __syncthreads();
    }
    unsigned run = t ? lds[t - 1] : 0u;
#pragma unroll
    for (int c = 0; c < 4; c++) {
        int i = t * 4 + c;
        if (i < NB) bstart[i] = run;
        run += v[c];
    }
    if (t == 255) bstart[NB] = (unsigned)E;
}

// Per-row exclusive scan of gcnt along b -> gbase[k][b]. One block per k.
__global__ __launch_bounds__(256) void rowscan_kernel(
    const unsigned* __restrict__ gcnt, unsigned* __restrict__ gbase)
{
    __shared__ unsigned lds[256];
    int k = blockIdx.x, t = threadIdx.x;
    unsigned v0 = gcnt[(size_t)k * EB + 2 * t];
    unsigned v1 = gcnt[(size_t)k * EB + 2 * t + 1];
    lds[t] = v0 + v1;
    __syncthreads();
    for (int d = 1; d < 256; d <<= 1) {
        unsigned x = (t >= d) ? lds[t - d] : 0u;
        __syncthreads();
        lds[t] += x;
        __syncthreads();
    }
    unsigned excl = t ? lds[t - 1] : 0u;
    gbase[(size_t)k * EB + 2 * t] = excl;
    gbase[(size_t)k * EB + 2 * t + 1] = excl + v0;
}

// Pass 2: block = (bin, slice of SW source blocks). Streams the slice's bin
// segments (contiguous runs, L3-resident) and places records at final
// bucket-major positions via 32 LDS cursors. Slices write disjoint per-bucket
// ranges [bstart[k]+gbase[k][b0], bstart[k]+gbase[k][b1]) -> race-free.
__global__ __launch_bounds__(256) void pass2_kernel(
    const unsigned* __restrict__ gbase,
    const unsigned* __restrict__ bstart,
    const unsigned* __restrict__ s1addr,
    const uvec4* __restrict__ src,
    uvec4* __restrict__ dst,
    int E, int NB)
{
    __shared__ unsigned sa[SW];
    __shared__ unsigned spref[SW + 1];
    __shared__ unsigned cur2[32];
    int bin = blockIdx.x / SLICES;
    int sl = blockIdx.x % SLICES;
    int t = threadIdx.x;
    int NBIN = (NB + 31) >> 5;
    if (bin >= NBIN) return;
    int b0 = sl * SW;

    if (t < SW) {
        int b = b0 + t;
        unsigned st = s1addr[bin * EB + b];
        unsigned en;
        if (bin + 1 < NBIN) en = s1addr[(bin + 1) * EB + b];
        else en = (unsigned)((long long)E * (b + 1) / EB);
        sa[t] = st;
        spref[t] = en - st;               // length, scanned below
    }
    if (t < 32) {
        int k = bin * 32 + t;
        cur2[t] = (k < NB) ? (bstart[k] + gbase[(size_t)k * EB + b0]) : 0u;
    }
    __syncthreads();
    if (t == 0) {
        unsigned run = 0;
        for (int q = 0; q < SW; q++) { unsigned c = spref[q]; spref[q] = run; run += c; }
        spref[SW] = run;
    }
    __syncthreads();
    unsigned R = spref[SW];

    for (unsigned i = t; i < R; i += 256) {
        unsigned lo = 0, hi = SW;
#pragma unroll
        for (int s = 0; s < 4; s++) {     // log2(SW)
            unsigned mid = (lo + hi) >> 1;
            if (spref[mid] <= i) lo = mid; else hi = mid;
        }
        uvec4 p = src[sa[lo] + (i - spref[lo])];
        unsigned kk = p.w & 31u;
        unsigned pos = atomicAdd(&cur2[kk], 1u);
        dst[pos] = p;
    }
}

// ===================== rounds =====================

// wsth[n][j] = fp16( bm[j] + sum_k state[n][k] * Wm[k][j] ), dense 20B rows (4MB total)
__global__ __launch_bounds__(256) void wstate_kernel(
    const float* __restrict__ state, const float* __restrict__ Wm,
    const float* __restrict__ bm, __half* __restrict__ wsth, int N)
{
    int n = blockIdx.x * blockDim.x + threadIdx.x;
    if (n >= N) return;
    const float2* sp = (const float2*)(state + (size_t)n * SD);
    float s[SD];
#pragma unroll
    for (int h = 0; h < 5; h++) { float2 v = sp[h]; s[2*h] = v.x; s[2*h+1] = v.y; }
    float t[SD];
#pragma unroll
    for (int j = 0; j < SD; j++) t[j] = bm[j];
#pragma unroll
    for (int k = 0; k < SD; k++) {
#pragma unroll
        for (int j = 0; j < SD; j++) t[j] += s[k] * Wm[k * SD + j];
    }
    unsigned* dp = (unsigned*)(wsth + (size_t)n * SD);   // 20B rows, 4B aligned
#pragma unroll
    for (int h = 0; h < 5; h++) {
        U32H2 cv;
        cv.h = __floats2half2_rn(t[2*h], t[2*h+1]);
        dp[h] = cv.u;
    }
}

// Run-accumulating round kernel: 10 lanes/edge, 6 edges/wave-step; each wave owns a
// CONTIGUOUS quarter of its bucket's edges. Within-bucket order is arbitrary
// (pass 2 doesn't lnt-sort): run-accumulation degrades to ~per-edge LDS atomics,
// measured cheap (round-2: SQ_LDS_BANK_CONFLICT ~1e3). Payload is contiguous
// bucket-major and LLC-resident.
template <bool FIRST>
__global__ __launch_bounds__(256) void round_run_kernel(
    const unsigned* __restrict__ bstart,
    const uvec4* __restrict__ payload,
    const float* __restrict__ Wm,
    const float* __restrict__ bm,
    const __half* __restrict__ wsth,      // (N,10) dense fp16, incl bias
    const float* __restrict__ state_prev,
    float* __restrict__ state_next,
    int N, int E)
{
    __shared__ float acc[BSZ * SD];       // 10 KB
    int k = blockIdx.x;
    for (int i = threadIdx.x; i < BSZ * SD; i += 256) acc[i] = 0.0f;

    int lane = threadIdx.x & 63;
    int wv = threadIdx.x >> 6;            // 0..3
    int grp0 = lane / 10;
    bool active = grp0 < 6;
    int grp = active ? grp0 : 5;
    int j = active ? (lane - grp0 * 10) : (lane - 60);

    float w0 = Wm[10 * SD + j];
    float w1 = Wm[11 * SD + j];
    float w2 = Wm[12 * SD + j];
    float w3 = Wm[13 * SD + j];
    float bb = bm[j];
    __syncthreads();

    unsigned beg = bstart[k], end = bstart[k + 1];
    unsigned len = end - beg;
    unsigned Q = (len + 3) >> 2;
    unsigned rbeg = beg + (unsigned)wv * Q;
    unsigned rend = rbeg + Q; if (rend > end) rend = end;
    unsigned eclamp = (unsigned)E - 1u;

    // pipeline preload: payload depth 2, wst depth 1
    unsigned e0 = rbeg + (unsigned)grp;
    uvec4 P0 = payload[e0 <= eclamp ? e0 : eclamp];
    unsigned e1 = e0 + 6;
    uvec4 P1 = payload[e1 <= eclamp ? e1 : eclamp];
    float T0 = bb, T1 = bb;
    if (!FIRST) T0 = __half2float(wsth[(size_t)(P0.x & 0x3FFFFu) * SD + j]);

    int cur_lnt = -1;
    float accv = 0.0f;

    for (unsigned base = rbeg; base < rend; base += 6) {
        unsigned e2 = base + 12 + (unsigned)grp;
        uvec4 P2 = payload[e2 <= eclamp ? e2 : eclamp];
        if (!FIRST) T1 = __half2float(wsth[(size_t)(P1.x & 0x3FFFFu) * SD + j]);
        unsigned e = base + (unsigned)grp;
        if (active && e < rend) {
            int lnt = (int)((P0.x >> 18) & (BSZ - 1));
            U32H2 c01, c23;
            c01.u = P0.y; c23.u = P0.z;
            float g0 = __low2float(c01.h), g1 = __high2float(c01.h);
            float g2 = __low2float(c23.h), g3 = __high2float(c23.h);
            float t = T0 + g0 * w0 + g1 * w1 + g2 * w2 + g3 * w3;
            if (lnt != cur_lnt) {
                if (cur_lnt >= 0) atomicAdd(&acc[cur_lnt * SD + j], accv);
                accv = 0.0f;
                cur_lnt = lnt;
            }
            accv += tanh_fast(t);
        }
        P0 = P1; P1 = P2; T0 = T1;
    }
    if (active && cur_lnt >= 0) atomicAdd(&acc[cur_lnt * SD + j], accv);
    __syncthreads();

    int base_o = k * BSZ * SD;
    int lim = N * SD - base_o;
    for (int i = threadIdx.x; i < BSZ * SD; i += 256) {
        if (i < lim) {
            float v = acc[i];
            if (!FIRST) v += state_prev[base_o + i];
            state_next[base_o + i] = v;
        }
    }
}

// ===================== graph phase =====================

__global__ __launch_bounds__(256) void goff_kernel(
    const int* __restrict__ gidx, unsigned* __restrict__ goff, int N, int G)
{
    int n = blockIdx.x * blockDim.x + threadIdx.x;
    if (n >= N) return;
    int g = gidx[n];
    if (n == 0) {
        for (int q = 0; q <= g; q++) goff[q] = 0;
    } else {
        int gp = gidx[n - 1];
        for (int q = gp + 1; q <= g; q++) goff[q] = (unsigned)n;
    }
    if (n == N - 1) {
        for (int q = g + 1; q <= G; q++) goff[q] = (unsigned)N;
    }
}

// 4-way split per (g,j); one atomic per partial. gstate must be zeroed.
__global__ __launch_bounds__(256) void gsum_kernel(
    const float* __restrict__ state, const unsigned* __restrict__ goff,
    float* __restrict__ gstate, int G)
{
    int tid = blockIdx.x * blockDim.x + threadIdx.x;
    if (tid >= G * SD * 4) return;
    int s = tid & 3;
    int rest = tid >> 2;
    int g = rest / SD;
    int j = rest - g * SD;
    unsigned beg = goff[g], end = goff[g + 1];
    unsigned len = end - beg;
    unsigned b0 = beg + (len * (unsigned)s) / 4u;
    unsigned b1 = beg + (len * (unsigned)(s + 1)) / 4u;
    float a = 0.0f;
    for (unsigned n = b0; n < b1; n++) a += state[(size_t)n * SD + j];
    atomicAdd(&gstate[(size_t)g * SD + j], a);
}

__global__ __launch_bounds__(256) void out_kernel(
    const float* __restrict__ gstate, const float* __restrict__ Wo,
    const float* __restrict__ bo, float* __restrict__ out, int G)
{
    int g = blockIdx.x * blockDim.x + threadIdx.x;
    if (g >= G) return;
    float s[SD];
#pragma unroll
    for (int k = 0; k < SD; k++) s[k] = gstate[(size_t)g * SD + k];
    float ev[4];
#pragma unroll
    for (int c = 0; c < 4; c++) {
        float a = bo[c];
#pragma unroll
        for (int k = 0; k < SD; k++) a += s[k] * Wo[k * 4 + c];
        ev[c] = a;
    }
    out[g * 4 + 0] = ev[0];
    out[g * 4 + 1] = softplus_f(ev[1]);
    out[g * 4 + 2] = softplus_f(ev[2]) + 1.0f;
    out[g * 4 + 3] = softplus_f(ev[3]);
}

// ===================== fallback (atomic path) =====================

template <bool FIRST>
__global__ __launch_bounds__(256) void edge_kernel_fb(
    const float* __restrict__ coords, const float* __restrict__ elen,
    const float* __restrict__ evec, const float* __restrict__ Wm,
    const float* __restrict__ bm, const int* __restrict__ nfrom,
    const int* __restrict__ nto, const float* __restrict__ state_prev,
    float* __restrict__ state_next, int E)
{
    int e = blockIdx.x * blockDim.x + threadIdx.x;
    if (e >= E) return;
    int nf = nfrom[e];
    int nt = nto[e];
    float cf0 = coords[nf*3+0], cf1 = coords[nf*3+1], cf2 = coords[nf*3+2];
    float ct0 = coords[nt*3+0], ct1 = coords[nt*3+1], ct2 = coords[nt*3+2];
    float ev0 = evec[e*3+0], ev1 = evec[e*3+1], ev2 = evec[e*3+2];
    float g0 = elen[e];
    float g1 = fabsf(cf0) + fabsf(cf1) + fabsf(cf2);
    float g2 = cf0*ct0 + cf1*ct1 + cf2*ct2;
    float g3 = cf0*ev0 + cf1*ev1 + cf2*ev2;
    float acc[SD];
#pragma unroll
    for (int j = 0; j < SD; j++) {
        acc[j] = bm[j] + g0*Wm[10*SD+j] + g1*Wm[11*SD+j] + g2*Wm[12*SD+j] + g3*Wm[13*SD+j];
    }
    if (!FIRST) {
        const float2* sp = (const float2*)(state_prev + (size_t)nf * SD);
        float s[SD];
#pragma unroll
        for (int h = 0; h < 5; h++) { float2 v = sp[h]; s[2*h] = v.x; s[2*h+1] = v.y; }
#pragma unroll
        for (int k = 0; k < SD; k++) {
#pragma unroll
            for (int j = 0; j < SD; j++) acc[j] += s[k] * Wm[k*SD+j];
        }
    }
    float* dst = state_next + (size_t)nt * SD;
#pragma unroll
    for (int j = 0; j < SD; j++) atomicAdd(dst + j, tanh_fast(acc[j]));
}

__global__ __launch_bounds__(256) void graph_reduce_fb(
    const float* __restrict__ state, const int* __restrict__ gidx,
    float* __restrict__ gstate, int N)
{
    int n = blockIdx.x * blockDim.x + threadIdx.x;
    if (n >= N) return;
    int g = gidx[n];
    const float2* sp = (const float2*)(state + (size_t)n * SD);
    float* dst = gstate + (size_t)g * SD;
#pragma unroll
    for (int h = 0; h < 5; h++) {
        float2 v = sp[h];
        atomicAdd(dst + 2*h, v.x);
        atomicAdd(dst + 2*h + 1, v.y);
    }
}

// ===================== launch =====================

extern "C" void kernel_launch(void* const* d_in, const int* in_sizes, int n_in,
                              void* d_out, int out_size, void* d_ws, size_t ws_size,
                              hipStream_t stream) {
    const float* coords = (const float*)d_in[0];
    const float* elen   = (const float*)d_in[1];
    const float* evec   = (const float*)d_in[2];
    const float* Wm     = (const float*)d_in[3];
    const float* bm     = (const float*)d_in[4];
    const float* Wo     = (const float*)d_in[5];
    const float* bo     = (const float*)d_in[6];
    const int* nfrom    = (const int*)d_in[7];
    const int* nto      = (const int*)d_in[8];
    const int* gidx     = (const int*)d_in[9];

    const int E = in_sizes[1];
    const int N = in_sizes[9];
    const int G = out_size / 4;

    const int NB = (N + BSZ - 1) / BSZ;      // fine buckets
    const int NBIN = (NB + 31) >> 5;         // coarse bins
    const size_t M = (size_t)NB * EB;        // per-(bucket,block) table size

    const int BLK = 256;
    const int ng = (N + BLK - 1) / BLK;
    const int gg = (G + BLK - 1) / BLK;

    auto align256 = [](size_t x) { return (x + 255) & ~(size_t)255; };
    const size_t state_bytes = align256((size_t)N * SD * sizeof(float));
    const size_t wst_bytes   = align256((size_t)N * SD * sizeof(__half) + 256);
    const size_t pay_bytes   = align256((size_t)E * sizeof(uvec4));
    const size_t gcnt_bytes  = align256(M * sizeof(unsigned));
    const size_t bsum_bytes  = align256((size_t)NB * sizeof(unsigned));
    const size_t bst_bytes   = align256((size_t)(NB + 1) * sizeof(unsigned));
    const size_t s1a_bytes   = align256((size_t)NBIN_MAX * EB * sizeof(unsigned));
    const size_t goff_bytes  = align256((size_t)(G + 1) * sizeof(unsigned));
    const size_t gst_bytes   = align256((size_t)G * SD * sizeof(float));
    const size_t c4_bytes    = align256((size_t)N * sizeof(float4));

    size_t o = 0;
    char* w = (char*)d_ws;
    float* stateA    = (float*)(w + o);    o += state_bytes;
    float* stateB    = (float*)(w + o);    o += state_bytes;
    __half* wsth     = (__half*)(w + o);   o += wst_bytes;
    uvec4* payA      = (uvec4*)(w + o);    o += pay_bytes;   // bin-sorted block-major
    uvec4* payB      = (uvec4*)(w + o);    o += pay_bytes;   // bucket-major final
    unsigned* gcnt   = (unsigned*)(w + o); o += gcnt_bytes;
    unsigned* gbase  = (unsigned*)(w + o); o += gcnt_bytes;
    unsigned* bsum   = (unsigned*)(w + o); o += bsum_bytes;
    unsigned* bstart = (unsigned*)(w + o); o += bst_bytes;
    unsigned* s1addr = (unsigned*)(w + o); o += s1a_bytes;
    unsigned* goff   = (unsigned*)(w + o); o += goff_bytes;
    float* gstate    = (float*)(w + o);    o += gst_bytes;
    float4* coords4  = (float4*)(w + o);   o += c4_bytes;

    if (o <= ws_size && NB <= MAXNB && N < (1 << 18)) {
        // ---- prep + build (2-pass radix partition, no global atomics) ----
        coords4_kernel<<<ng, BLK, 0, stream>>>(coords, coords4, N);
        pass1_kernel<<<EB, CTHR, 0, stream>>>(coords4, elen, evec, nfrom, nto,
                                              gcnt, s1addr, payA, E, NB);
        rowsum_kernel<<<NB, 256, 0, stream>>>(gcnt, bsum);
        bscan_kernel<<<1, 256, 0, stream>>>(bsum, bstart, NB, E);
        rowscan_kernel<<<NB, 256, 0, stream>>>(gcnt, gbase);
        pass2_kernel<<<NBIN * SLICES, 256, 0, stream>>>(gbase, bstart, s1addr,
                                                        payA, payB, E, NB);
        // ---- rounds (contiguous bucket-major, LLC-resident payload) ----
        round_run_kernel<true><<<NB, BLK, 0, stream>>>(bstart, payB, Wm, bm,
                                                       wsth, stateB, stateA, N, E);
        wstate_kernel<<<ng, BLK, 0, stream>>>(stateA, Wm, bm, wsth, N);
        round_run_kernel<false><<<NB, BLK, 0, stream>>>(bstart, payB, Wm, bm,
                                                        wsth, stateA, stateB, N, E);
        wstate_kernel<<<ng, BLK, 0, stream>>>(stateB, Wm, bm, wsth, N);
        round_run_kernel<false><<<NB, BLK, 0, stream>>>(bstart, payB, Wm, bm,
                                                        wsth, stateB, stateA, N, E);
        // ---- graph phase ----
        hipMemsetAsync(gstate, 0, (size_t)G * SD * sizeof(float), stream);
        goff_kernel<<<ng, BLK, 0, stream>>>(gidx, goff, N, G);
        gsum_kernel<<<(G * SD * 4 + BLK - 1) / BLK, BLK, 0, stream>>>(stateA, goff, gstate, G);
        out_kernel<<<gg, BLK, 0, stream>>>(gstate, Wo, bo, (float*)d_out, G);
    } else {
        // ---- fallback: atomic path ----
        const int eg = (E + BLK - 1) / BLK;
        float* gstateF = (float*)(w + 2 * state_bytes);
        hipMemsetAsync(stateA, 0, state_bytes, stream);
        hipMemsetAsync(gstateF, 0, (size_t)G * SD * sizeof(float), stream);
        edge_kernel_fb<true><<<eg, BLK, 0, stream>>>(coords, elen, evec, Wm, bm,
                                                     nfrom, nto, stateA, stateA, E);
        hipMemcpyAsync(stateB, stateA, state_bytes, hipMemcpyDeviceToDevice, stream);
        edge_kernel_fb<false><<<eg, BLK, 0, stream>>>(coords, elen, evec, Wm, bm,
                                                      nfrom, nto, stateA, stateB, E);
        hipMemcpyAsync(stateA, stateB, state_bytes, hipMemcpyDeviceToDevice, stream);
        edge_kernel_fb<false><<<eg, BLK, 0, stream>>>(coords, elen, evec, Wm, bm,
                                                      nfrom, nto, stateB, stateA, E);
        graph_reduce_fb<<<ng, BLK, 0, stream>>>(stateA, gidx, gstateF, N);
        out_kernel<<<gg, BLK, 0, stream>>>(gstateF, Wo, bo, (float*)d_out, G);
    }
}

// Round 6
// 725.975 us; speedup vs baseline: 2.3498x; 2.3498x over previous
//
#include <hip/hip_runtime.h>
#include <hip/hip_fp16.h>
#include <math.h>

#define SD 10
#define BSZ 64                // round-kernel bucket (nodes per round block)
#define EB 512                // edge-chunk blocks (pass-1 grid)
#define CTHR 1024             // threads for pass1/pass2
#define BINB 10               // bin bits: 1024 nodes per bin
#define NBIN_MAX 256          // N <= 256*1024 = 262144 (and N < 2^18 gate)

typedef unsigned uvec4 __attribute__((ext_vector_type(4)));
struct rec12 { unsigned x, y, z; };   // 12B packed payload (sizeof==12, align 4)
union U32H2 { unsigned u; __half2 h; };

__device__ __forceinline__ float tanh_fast(float x) {
    float e = __expf(2.0f * x);
    float r = __builtin_amdgcn_rcpf(1.0f + e);
    return 1.0f - 2.0f * r;
}

__device__ __forceinline__ float softplus_f(float x) {
    return fmaxf(x, 0.0f) + log1pf(expf(-fabsf(x)));
}

// ===================== prep =====================

__global__ __launch_bounds__(256) void coords4_kernel(
    const float* __restrict__ coords, float4* __restrict__ coords4, int N)
{
    int n = blockIdx.x * blockDim.x + threadIdx.x;
    if (n >= N) return;
    float4 c;
    c.x = coords[n * 3 + 0];
    c.y = coords[n * 3 + 1];
    c.z = coords[n * 3 + 2];
    c.w = 0.0f;
    coords4[n] = c;
}

// ===================== build: 2-pass radix with full nt-sort =====================
// L2-footprint invariant (rounds 0-5 lesson): scatter frontier =
// resident_blocks_per_XCD x targets x 128B must be << 4MB L2.
// Pass1: 196 bin targets x 64 resident = 1.6MB OK. Pass2: 1024 cursors but the
// write window per block is a contiguous ~400KB region (frontier ~3MB chip-wide) OK.

// Pass 1: block b splits its chunk [ebeg,eend) by 1024-node bin, contiguous emit.
// One random gather (cf = coords4[nf]); computes g0,g1,g3; carries cf fp16 for g2.
// Record: x = nf | (nt&1023)<<18 ; y = h2(g0,g1) ; z = h2(g3,cfx) ; w = h2(cfy,cfz).
// Emits s1addr[bin][b] = segment start; sentinel row s1addr[NBIN][b] = chunk end.
__global__ __launch_bounds__(CTHR) void pass1_kernel(
    const float4* __restrict__ coords4,
    const float* __restrict__ elen,
    const float* __restrict__ evec,
    const int* __restrict__ nfrom,
    const int* __restrict__ nto,
    unsigned* __restrict__ s1addr,
    uvec4* __restrict__ payA,
    int E, int NBIN)
{
    __shared__ unsigned hbin[NBIN_MAX];
    __shared__ unsigned curbin[NBIN_MAX];
    int b = blockIdx.x, t = threadIdx.x;
    long long ebeg = (long long)E * b / EB;
    long long eend = (long long)E * (b + 1) / EB;

    if (t < NBIN_MAX) hbin[t] = 0;
    __syncthreads();
    for (long long e = ebeg + t; e < eend; e += CTHR)
        atomicAdd(&hbin[((unsigned)nto[e]) >> BINB], 1u);
    __syncthreads();
    {   // exclusive scan of hbin -> curbin (lanes t < NBIN_MAX)
        unsigned v = (t < NBIN_MAX) ? hbin[t] : 0u;
        for (int d = 1; d < NBIN_MAX; d <<= 1) {
            unsigned x = (t < NBIN_MAX && t >= d) ? hbin[t - d] : 0u;
            __syncthreads();
            if (t < NBIN_MAX) hbin[t] += x;
            __syncthreads();
        }
        if (t < NBIN_MAX) curbin[t] = (unsigned)ebeg + hbin[t] - v;
    }
    __syncthreads();
    if (t < NBIN) s1addr[(size_t)t * EB + b] = curbin[t];
    if (t == 0)  s1addr[(size_t)NBIN * EB + b] = (unsigned)eend;
    __syncthreads();

    // emit with 2-deep software pipeline (hide the cf gather)
    long long e = ebeg + t;
    if (e < eend) {
        int nf0 = nfrom[e], nt0 = nto[e];
        float4 cf0 = coords4[nf0];
        float l0 = elen[e];
        float ex0 = evec[e*3+0], ey0 = evec[e*3+1], ez0 = evec[e*3+2];
        while (true) {
            long long e1 = e + CTHR;
            bool has1 = e1 < eend;
            int nf1 = 0, nt1 = 0; float4 cf1 = cf0;
            float l1 = 0, ex1 = 0, ey1 = 0, ez1 = 0;
            if (has1) {
                nf1 = nfrom[e1]; nt1 = nto[e1];
                cf1 = coords4[nf1];
                l1 = elen[e1]; ex1 = evec[e1*3+0]; ey1 = evec[e1*3+1]; ez1 = evec[e1*3+2];
            }
            unsigned bin = ((unsigned)nt0) >> BINB;
            unsigned pos = atomicAdd(&curbin[bin], 1u);
            float g1 = fabsf(cf0.x) + fabsf(cf0.y) + fabsf(cf0.z);
            float g3 = cf0.x * ex0 + cf0.y * ey0 + cf0.z * ez0;
            U32H2 a, c, d;
            a.h = __floats2half2_rn(l0, g1);
            c.h = __floats2half2_rn(g3, cf0.x);
            d.h = __floats2half2_rn(cf0.y, cf0.z);
            uvec4 p;
            p.x = (unsigned)nf0 | (((unsigned)nt0 & ((1u << BINB) - 1u)) << 18);
            p.y = a.u; p.z = c.u; p.w = d.u;
            payA[pos] = p;
            if (!has1) break;
            e = e1; nf0 = nf1; nt0 = nt1; cf0 = cf1;
            l0 = l1; ex0 = ex1; ey0 = ey1; ez0 = ez1;
        }
    }
}

// Column sums of s1addr rows -> binsum[q] (q = 0..NBIN). EB==512, 256 thr: 2 each.
__global__ __launch_bounds__(256) void colsum_kernel(
    const unsigned* __restrict__ s1addr, unsigned* __restrict__ binsum)
{
    __shared__ unsigned red[256];
    int q = blockIdx.x, t = threadIdx.x;
    red[t] = s1addr[(size_t)q * EB + t] + s1addr[(size_t)q * EB + t + 256];
    __syncthreads();
    for (int d = 128; d > 0; d >>= 1) {
        if (t < d) red[t] += red[t + d];
        __syncthreads();
    }
    if (t == 0) binsum[q] = red[0];
}

// binstart[q] = binsum[q] - binsum[0]  (since s1addr[0][b] = chunk start).
// Also writes the nodestart sentinel at NBIN<<BINB.
__global__ __launch_bounds__(256) void binstart_kernel(
    const unsigned* __restrict__ binsum, unsigned* __restrict__ binstart,
    unsigned* __restrict__ nodestart, int NBIN, int E)
{
    int t = threadIdx.x;
    unsigned b0 = binsum[0];
    for (int q = t; q <= NBIN; q += 256) binstart[q] = binsum[q] - b0;
    if (t == 0) nodestart[(size_t)NBIN << BINB] = (unsigned)E;
}

// Pass 2: one block per bin (1024 nodes). Two coalesced passes over the bin's
// 512 segments (binary search on the LDS segment table): (A) histogram nt&1023,
// (B) LDS-scan -> cursors (+ nodestart CSR emit), then place records FULLY
// nt-sorted into a contiguous window of dst. Computes g2 here: ct = coords4[nt]
// hits a 16KB L1-resident window. Output record (12B): x = nf | (nt&63)<<18,
// y = h2(g0,g1), z = h2(g2,g3).
__global__ __launch_bounds__(CTHR) void pass2_kernel(
    const unsigned* __restrict__ s1addr,
    const unsigned* __restrict__ binstart,
    const float4* __restrict__ coords4,
    const uvec4* __restrict__ src,
    rec12* __restrict__ dst,
    unsigned* __restrict__ nodestart,
    int NBIN)
{
    __shared__ unsigned segst[EB];        // 2 KB
    __shared__ unsigned spref[EB + 1];    // 2 KB
    __shared__ unsigned hist[1 << BINB];  // 4 KB
    __shared__ unsigned cur[1 << BINB];   // 4 KB
    int q = blockIdx.x, t = threadIdx.x;

    if (t < EB) {
        unsigned st = s1addr[(size_t)q * EB + t];
        unsigned en = s1addr[(size_t)(q + 1) * EB + t];
        segst[t] = st;
        spref[t] = en - st;
    }
    hist[t] = 0;
    __syncthreads();
    {   // exclusive scan of the 512 segment lengths
        unsigned v = (t < EB) ? spref[t] : 0u;
        for (int d = 1; d < EB; d <<= 1) {
            unsigned x = (t < EB && t >= d) ? spref[t - d] : 0u;
            __syncthreads();
            if (t < EB) spref[t] += x;
            __syncthreads();
        }
        unsigned incl = (t < EB) ? spref[t] : 0u;
        __syncthreads();
        if (t < EB) spref[t] = incl - v;
        if (t == EB - 1) spref[EB] = incl;
    }
    __syncthreads();
    unsigned len = spref[EB];
    unsigned obase = binstart[q];
    const unsigned* srcw = (const unsigned*)src;

    // pass A: histogram keys (reads only word0 of each record)
    for (unsigned i = t; i < len; i += CTHR) {
        unsigned lo = 0, hi = EB;
#pragma unroll
        for (int s = 0; s < 9; s++) {
            unsigned mid = (lo + hi) >> 1;
            if (spref[mid] <= i) lo = mid; else hi = mid;
        }
        unsigned x0 = srcw[(size_t)(segst[lo] + (i - spref[lo])) * 4];
        atomicAdd(&hist[(x0 >> 18) & ((1u << BINB) - 1u)], 1u);
    }
    __syncthreads();
    // scan 1024-key histogram (inclusive, in place), 1024 threads
    unsigned hv = hist[t];
    __syncthreads();
    for (int d = 1; d < (1 << BINB); d <<= 1) {
        unsigned x = (t >= d) ? hist[t - d] : 0u;
        __syncthreads();
        hist[t] += x;
        __syncthreads();
    }
    unsigned excl = hist[t] - hv;
    cur[t] = obase + excl;
    nodestart[((size_t)q << BINB) + t] = obase + excl;   // node-level CSR
    __syncthreads();

    // pass B: place records nt-sorted; compute g2 with L1-local ct gather
    for (unsigned i = t; i < len; i += CTHR) {
        unsigned lo = 0, hi = EB;
#pragma unroll
        for (int s = 0; s < 9; s++) {
            unsigned mid = (lo + hi) >> 1;
            if (spref[mid] <= i) lo = mid; else hi = mid;
        }
        uvec4 p = src[segst[lo] + (i - spref[lo])];
        unsigned key = (p.x >> 18) & ((1u << BINB) - 1u);
        unsigned pos = atomicAdd(&cur[key], 1u);
        unsigned nt = ((unsigned)q << BINB) | key;
        float4 ct = coords4[nt];
        U32H2 zc, wc;
        zc.u = p.z; wc.u = p.w;
        float g3 = __low2float(zc.h);
        float cfx = __high2float(zc.h);
        float cfy = __low2float(wc.h), cfz = __high2float(wc.h);
        float g2 = cfx * ct.x + cfy * ct.y + cfz * ct.z;
        U32H2 o; o.h = __floats2half2_rn(g2, g3);
        rec12 r;
        r.x = (p.x & 0x3FFFFu) | ((nt & (BSZ - 1u)) << 18);
        r.y = p.y;
        r.z = o.u;
        dst[pos] = r;
    }
}

// ===================== rounds =====================

// wsth[n][j] = fp16( bm[j] + sum_k state[n][k] * Wm[k][j] ), dense 20B rows (4MB total)
__global__ __launch_bounds__(256) void wstate_kernel(
    const float* __restrict__ state, const float* __restrict__ Wm,
    const float* __restrict__ bm, __half* __restrict__ wsth, int N)
{
    int n = blockIdx.x * blockDim.x + threadIdx.x;
    if (n >= N) return;
    const float2* sp = (const float2*)(state + (size_t)n * SD);
    float s[SD];
#pragma unroll
    for (int h = 0; h < 5; h++) { float2 v = sp[h]; s[2*h] = v.x; s[2*h+1] = v.y; }
    float t[SD];
#pragma unroll
    for (int j = 0; j < SD; j++) t[j] = bm[j];
#pragma unroll
    for (int k = 0; k < SD; k++) {
#pragma unroll
        for (int j = 0; j < SD; j++) t[j] += s[k] * Wm[k * SD + j];
    }
    unsigned* dp = (unsigned*)(wsth + (size_t)n * SD);   // 20B rows, 4B aligned
#pragma unroll
    for (int h = 0; h < 5; h++) {
        U32H2 cv;
        cv.h = __floats2half2_rn(t[2*h], t[2*h+1]);
        dp[h] = cv.u;
    }
}

// Run-accumulating round kernel (round-0 proven config): BSZ=64 -> grid ~3125,
// 8 blocks/CU. Payload is FULLY nt-sorted (runs ~32/node) -> LDS atomic only on
// run change. 12B records; bucket range from node-level CSR.
template <bool FIRST>
__global__ __launch_bounds__(256) void round_run_kernel(
    const unsigned* __restrict__ nodestart,
    const rec12* __restrict__ payload,
    const float* __restrict__ Wm,
    const float* __restrict__ bm,
    const __half* __restrict__ wsth,      // (N,10) dense fp16, incl bias
    const float* __restrict__ state_prev,
    float* __restrict__ state_next,
    int N, int E)
{
    __shared__ float acc[BSZ * SD];       // 2.56 KB
    int k = blockIdx.x;
    for (int i = threadIdx.x; i < BSZ * SD; i += 256) acc[i] = 0.0f;

    int lane = threadIdx.x & 63;
    int wv = threadIdx.x >> 6;            // 0..3
    int grp0 = lane / 10;
    bool active = grp0 < 6;
    int grp = active ? grp0 : 5;
    int j = active ? (lane - grp0 * 10) : (lane - 60);

    float w0 = Wm[10 * SD + j];
    float w1 = Wm[11 * SD + j];
    float w2 = Wm[12 * SD + j];
    float w3 = Wm[13 * SD + j];
    float bb = bm[j];
    __syncthreads();

    unsigned beg = nodestart[(size_t)k << 6];
    unsigned end = nodestart[(size_t)(k + 1) << 6];
    unsigned len = end - beg;
    unsigned Q = (len + 3) >> 2;
    unsigned rbeg = beg + (unsigned)wv * Q;
    unsigned rend = rbeg + Q; if (rend > end) rend = end;
    unsigned eclamp = (unsigned)E - 1u;

    // pipeline preload: payload depth 2, wst depth 1
    unsigned e0 = rbeg + (unsigned)grp;
    rec12 P0 = payload[e0 <= eclamp ? e0 : eclamp];
    unsigned e1 = e0 + 6;
    rec12 P1 = payload[e1 <= eclamp ? e1 : eclamp];
    float T0 = bb, T1 = bb;
    if (!FIRST) T0 = __half2float(wsth[(size_t)(P0.x & 0x3FFFFu) * SD + j]);

    int cur_lnt = -1;
    float accv = 0.0f;

    for (unsigned base = rbeg; base < rend; base += 6) {
        unsigned e2 = base + 12 + (unsigned)grp;
        rec12 P2 = payload[e2 <= eclamp ? e2 : eclamp];
        if (!FIRST) T1 = __half2float(wsth[(size_t)(P1.x & 0x3FFFFu) * SD + j]);
        unsigned e = base + (unsigned)grp;
        if (active && e < rend) {
            int lnt = (int)((P0.x >> 18) & (BSZ - 1));
            U32H2 c01, c23;
            c01.u = P0.y; c23.u = P0.z;
            float g0 = __low2float(c01.h), g1 = __high2float(c01.h);
            float g2 = __low2float(c23.h), g3 = __high2float(c23.h);
            float t = T0 + g0 * w0 + g1 * w1 + g2 * w2 + g3 * w3;
            if (lnt != cur_lnt) {
                if (cur_lnt >= 0) atomicAdd(&acc[cur_lnt * SD + j], accv);
                accv = 0.0f;
                cur_lnt = lnt;
            }
            accv += tanh_fast(t);
        }
        P0 = P1; P1 = P2; T0 = T1;
    }
    if (active && cur_lnt >= 0) atomicAdd(&acc[cur_lnt * SD + j], accv);
    __syncthreads();

    int base_o = k * BSZ * SD;
    int lim = N * SD - base_o;
    for (int i = threadIdx.x; i < BSZ * SD; i += 256) {
        if (i < lim) {
            float v = acc[i];
            if (!FIRST) v += state_prev[base_o + i];
            state_next[base_o + i] = v;
        }
    }
}

// ===================== graph phase =====================

__global__ __launch_bounds__(256) void goff_kernel(
    const int* __restrict__ gidx, unsigned* __restrict__ goff, int N, int G)
{
    int n = blockIdx.x * blockDim.x + threadIdx.x;
    if (n >= N) return;
    int g = gidx[n];
    if (n == 0) {
        for (int q = 0; q <= g; q++) goff[q] = 0;
    } else {
        int gp = gidx[n - 1];
        for (int q = gp + 1; q <= g; q++) goff[q] = (unsigned)n;
    }
    if (n == N - 1) {
        for (int q = g + 1; q <= G; q++) goff[q] = (unsigned)N;
    }
}

// 4-way split per (g,j); one atomic per partial. gstate must be zeroed.
__global__ __launch_bounds__(256) void gsum_kernel(
    const float* __restrict__ state, const unsigned* __restrict__ goff,
    float* __restrict__ gstate, int G)
{
    int tid = blockIdx.x * blockDim.x + threadIdx.x;
    if (tid >= G * SD * 4) return;
    int s = tid & 3;
    int rest = tid >> 2;
    int g = rest / SD;
    int j = rest - g * SD;
    unsigned beg = goff[g], end = goff[g + 1];
    unsigned len = end - beg;
    unsigned b0 = beg + (len * (unsigned)s) / 4u;
    unsigned b1 = beg + (len * (unsigned)(s + 1)) / 4u;
    float a = 0.0f;
    for (unsigned n = b0; n < b1; n++) a += state[(size_t)n * SD + j];
    atomicAdd(&gstate[(size_t)g * SD + j], a);
}

__global__ __launch_bounds__(256) void out_kernel(
    const float* __restrict__ gstate, const float* __restrict__ Wo,
    const float* __restrict__ bo, float* __restrict__ out, int G)
{
    int g = blockIdx.x * blockDim.x + threadIdx.x;
    if (g >= G) return;
    float s[SD];
#pragma unroll
    for (int k = 0; k < SD; k++) s[k] = gstate[(size_t)g * SD + k];
    float ev[4];
#pragma unroll
    for (int c = 0; c < 4; c++) {
        float a = bo[c];
#pragma unroll
        for (int k = 0; k < SD; k++) a += s[k] * Wo[k * 4 + c];
        ev[c] = a;
    }
    out[g * 4 + 0] = ev[0];
    out[g * 4 + 1] = softplus_f(ev[1]);
    out[g * 4 + 2] = softplus_f(ev[2]) + 1.0f;
    out[g * 4 + 3] = softplus_f(ev[3]);
}

// ===================== fallback (atomic path) =====================

template <bool FIRST>
__global__ __launch_bounds__(256) void edge_kernel_fb(
    const float* __restrict__ coords, const float* __restrict__ elen,
    const float* __restrict__ evec, const float* __restrict__ Wm,
    const float* __restrict__ bm, const int* __restrict__ nfrom,
    const int* __restrict__ nto, const float* __restrict__ state_prev,
    float* __restrict__ state_next, int E)
{
    int e = blockIdx.x * blockDim.x + threadIdx.x;
    if (e >= E) return;
    int nf = nfrom[e];
    int nt = nto[e];
    float cf0 = coords[nf*3+0], cf1 = coords[nf*3+1], cf2 = coords[nf*3+2];
    float ct0 = coords[nt*3+0], ct1 = coords[nt*3+1], ct2 = coords[nt*3+2];
    float ev0 = evec[e*3+0], ev1 = evec[e*3+1], ev2 = evec[e*3+2];
    float g0 = elen[e];
    float g1 = fabsf(cf0) + fabsf(cf1) + fabsf(cf2);
    float g2 = cf0*ct0 + cf1*ct1 + cf2*ct2;
    float g3 = cf0*ev0 + cf1*ev1 + cf2*ev2;
    float acc[SD];
#pragma unroll
    for (int j = 0; j < SD; j++) {
        acc[j] = bm[j] + g0*Wm[10*SD+j] + g1*Wm[11*SD+j] + g2*Wm[12*SD+j] + g3*Wm[13*SD+j];
    }
    if (!FIRST) {
        const float2* sp = (const float2*)(state_prev + (size_t)nf * SD);
        float s[SD];
#pragma unroll
        for (int h = 0; h < 5; h++) { float2 v = sp[h]; s[2*h] = v.x; s[2*h+1] = v.y; }
#pragma unroll
        for (int k = 0; k < SD; k++) {
#pragma unroll
            for (int j = 0; j < SD; j++) acc[j] += s[k] * Wm[k*SD+j];
        }
    }
    float* dst = state_next + (size_t)nt * SD;
#pragma unroll
    for (int j = 0; j < SD; j++) atomicAdd(dst + j, tanh_fast(acc[j]));
}

__global__ __launch_bounds__(256) void graph_reduce_fb(
    const float* __restrict__ state, const int* __restrict__ gidx,
    float* __restrict__ gstate, int N)
{
    int n = blockIdx.x * blockDim.x + threadIdx.x;
    if (n >= N) return;
    int g = gidx[n];
    const float2* sp = (const float2*)(state + (size_t)n * SD);
    float* dst = gstate + (size_t)g * SD;
#pragma unroll
    for (int h = 0; h < 5; h++) {
        float2 v = sp[h];
        atomicAdd(dst + 2*h, v.x);
        atomicAdd(dst + 2*h + 1, v.y);
    }
}

// ===================== launch =====================

extern "C" void kernel_launch(void* const* d_in, const int* in_sizes, int n_in,
                              void* d_out, int out_size, void* d_ws, size_t ws_size,
                              hipStream_t stream) {
    const float* coords = (const float*)d_in[0];
    const float* elen   = (const float*)d_in[1];
    const float* evec   = (const float*)d_in[2];
    const float* Wm     = (const float*)d_in[3];
    const float* bm     = (const float*)d_in[4];
    const float* Wo     = (const float*)d_in[5];
    const float* bo     = (const float*)d_in[6];
    const int* nfrom    = (const int*)d_in[7];
    const int* nto      = (const int*)d_in[8];
    const int* gidx     = (const int*)d_in[9];

    const int E = in_sizes[1];
    const int N = in_sizes[9];
    const int G = out_size / 4;

    const int NBIN = (N + (1 << BINB) - 1) >> BINB;   // bins (<= 256)
    const int NB   = (N + BSZ - 1) / BSZ;             // round buckets (~3125)

    const int BLK = 256;
    const int ng = (N + BLK - 1) / BLK;
    const int gg = (G + BLK - 1) / BLK;

    auto align256 = [](size_t x) { return (x + 255) & ~(size_t)255; };
    const size_t state_bytes = align256((size_t)N * SD * sizeof(float));
    const size_t wst_bytes   = align256((size_t)N * SD * sizeof(__half) + 256);
    const size_t payA_bytes  = align256((size_t)E * sizeof(uvec4));
    const size_t payB_bytes  = align256((size_t)E * sizeof(rec12) + 256);
    const size_t s1a_bytes   = align256((size_t)(NBIN_MAX + 1) * EB * sizeof(unsigned));
    const size_t bsum_bytes  = align256((size_t)(NBIN_MAX + 1) * sizeof(unsigned));
    const size_t nst_bytes   = align256(((size_t)NBIN_MAX * (1 << BINB) + 2) * sizeof(unsigned));
    const size_t goff_bytes  = align256((size_t)(G + 1) * sizeof(unsigned));
    const size_t gst_bytes   = align256((size_t)G * SD * sizeof(float));
    const size_t c4_bytes    = align256((size_t)N * sizeof(float4));

    size_t o = 0;
    char* w = (char*)d_ws;
    float* stateA      = (float*)(w + o);    o += state_bytes;
    float* stateB      = (float*)(w + o);    o += state_bytes;
    __half* wsth       = (__half*)(w + o);   o += wst_bytes;
    uvec4* payA        = (uvec4*)(w + o);    o += payA_bytes;   // bin-sorted block-major
    rec12* payB        = (rec12*)(w + o);    o += payB_bytes;   // fully nt-sorted
    unsigned* s1addr   = (unsigned*)(w + o); o += s1a_bytes;
    unsigned* binsum   = (unsigned*)(w + o); o += bsum_bytes;
    unsigned* binstart = (unsigned*)(w + o); o += bsum_bytes;
    unsigned* nodestart= (unsigned*)(w + o); o += nst_bytes;
    unsigned* goff     = (unsigned*)(w + o); o += goff_bytes;
    float* gstate      = (float*)(w + o);    o += gst_bytes;
    float4* coords4    = (float4*)(w + o);   o += c4_bytes;

    if (o <= ws_size && NBIN <= NBIN_MAX && N < (1 << 18)) {
        // ---- prep + build ----
        coords4_kernel<<<ng, BLK, 0, stream>>>(coords, coords4, N);
        pass1_kernel<<<EB, CTHR, 0, stream>>>(coords4, elen, evec, nfrom, nto,
                                              s1addr, payA, E, NBIN);
        colsum_kernel<<<NBIN + 1, 256, 0, stream>>>(s1addr, binsum);
        binstart_kernel<<<1, 256, 0, stream>>>(binsum, binstart, nodestart, NBIN, E);
        pass2_kernel<<<NBIN, CTHR, 0, stream>>>(s1addr, binstart, coords4,
                                                payA, payB, nodestart, NBIN);
        // ---- rounds (sorted 12B payload, high-occupancy 64-node buckets) ----
        round_run_kernel<true><<<NB, BLK, 0, stream>>>(nodestart, payB, Wm, bm,
                                                       wsth, stateB, stateA, N, E);
        wstate_kernel<<<ng, BLK, 0, stream>>>(stateA, Wm, bm, wsth, N);
        round_run_kernel<false><<<NB, BLK, 0, stream>>>(nodestart, payB, Wm, bm,
                                                        wsth, stateA, stateB, N, E);
        wstate_kernel<<<ng, BLK, 0, stream>>>(stateB, Wm, bm, wsth, N);
        round_run_kernel<false><<<NB, BLK, 0, stream>>>(nodestart, payB, Wm, bm,
                                                        wsth, stateB, stateA, N, E);
        // ---- graph phase ----
        hipMemsetAsync(gstate, 0, (size_t)G * SD * sizeof(float), stream);
        goff_kernel<<<ng, BLK, 0, stream>>>(gidx, goff, N, G);
        gsum_kernel<<<(G * SD * 4 + BLK - 1) / BLK, BLK, 0, stream>>>(stateA, goff, gstate, G);
        out_kernel<<<gg, BLK, 0, stream>>>(gstate, Wo, bo, (float*)d_out, G);
    } else {
        // ---- fallback: atomic path ----
        const int eg = (E + BLK - 1) / BLK;
        float* gstateF = (float*)(w + 2 * state_bytes);
        hipMemsetAsync(stateA, 0, state_bytes, stream);
        hipMemsetAsync(gstateF, 0, (size_t)G * SD * sizeof(float), stream);
        edge_kernel_fb<true><<<eg, BLK, 0, stream>>>(coords, elen, evec, Wm, bm,
                                                     nfrom, nto, stateA, stateA, E);
        hipMemcpyAsync(stateB, stateA, state_bytes, hipMemcpyDeviceToDevice, stream);
        edge_kernel_fb<false><<<eg, BLK, 0, stream>>>(coords, elen, evec, Wm, bm,
                                                      nfrom, nto, stateA, stateB, E);
        hipMemcpyAsync(stateA, stateB, state_bytes, hipMemcpyDeviceToDevice, stream);
        edge_kernel_fb<false><<<eg, BLK, 0, stream>>>(coords, elen, evec, Wm, bm,
                                                      nfrom, nto, stateB, stateA, E);
        graph_reduce_fb<<<ng, BLK, 0, stream>>>(stateA, gidx, gstateF, N);
        out_kernel<<<gg, BLK, 0, stream>>>(gstateF, Wo, bo, (float*)d_out, G);
    }
}

// Round 7
// 702.251 us; speedup vs baseline: 2.4291x; 1.0338x over previous
//
#include <hip/hip_runtime.h>
#include <hip/hip_fp16.h>
#include <math.h>

#define SD 10
#define BSZ 64                // round-kernel bucket (nodes per round block)
#define EB 512                // edge-chunk blocks (pass-1 grid)
#define CTHR 1024             // threads for pass1/pass2
#define BINB 10               // bin bits: 1024 nodes per bin
#define NBIN_MAX 256          // N <= 256*1024 = 262144 (and N < 2^18 gate)

typedef unsigned uvec4 __attribute__((ext_vector_type(4)));
struct rec12 { unsigned x, y, z; };   // 12B packed payload
union U32H2 { unsigned u; __half2 h; };

__device__ __forceinline__ float tanh_fast(float x) {
    float e = __expf(2.0f * x);
    float r = __builtin_amdgcn_rcpf(1.0f + e);
    return 1.0f - 2.0f * r;
}

__device__ __forceinline__ float softplus_f(float x) {
    return fmaxf(x, 0.0f) + log1pf(expf(-fabsf(x)));
}

// ===================== prep =====================

// coords4[n] = {x, y, z, g1=|x|+|y|+|z|}: g1 rides along with every cf gather.
__global__ __launch_bounds__(256) void coords4_kernel(
    const float* __restrict__ coords, float4* __restrict__ coords4, int N)
{
    int n = blockIdx.x * blockDim.x + threadIdx.x;
    if (n >= N) return;
    float4 c;
    c.x = coords[n * 3 + 0];
    c.y = coords[n * 3 + 1];
    c.z = coords[n * 3 + 2];
    c.w = fabsf(c.x) + fabsf(c.y) + fabsf(c.z);
    coords4[n] = c;
}

// ===================== build: 2-pass radix with full nt-sort =====================
// Division of labor (round-6 post-mortem): pass1 = PURE STREAMING split (no
// gathers, NT loads keep L2 clean for the 196-target write frontier); pass2 =
// all random gathers (cf over a 3.2MB L2-resident table, ct L1-local) + full
// nt-sort + feature computation, with block-private contiguous writes.

// Pass 1: block b splits its chunk [ebeg,eend) by 1024-node bin, contiguous emit.
// Record: x = nf | (nt&1023)<<18 ; y = h2(elen, ev0) ; z = h2(ev1, ev2).
// Emits s1addr[bin][b] = segment start; sentinel row s1addr[NBIN][b] = chunk end.
__global__ __launch_bounds__(CTHR) void pass1_kernel(
    const float* __restrict__ elen,
    const float* __restrict__ evec,
    const int* __restrict__ nfrom,
    const int* __restrict__ nto,
    unsigned* __restrict__ s1addr,
    rec12* __restrict__ payA,
    int E, int NBIN)
{
    __shared__ unsigned hbin[NBIN_MAX];
    __shared__ unsigned curbin[NBIN_MAX];
    int b = blockIdx.x, t = threadIdx.x;
    long long ebeg = (long long)E * b / EB;
    long long eend = (long long)E * (b + 1) / EB;

    if (t < NBIN_MAX) hbin[t] = 0;
    __syncthreads();
    for (long long e = ebeg + t; e < eend; e += CTHR)
        atomicAdd(&hbin[((unsigned)__builtin_nontemporal_load(&nto[e])) >> BINB], 1u);
    __syncthreads();
    {   // exclusive scan of hbin -> curbin (lanes t < NBIN_MAX)
        unsigned v = (t < NBIN_MAX) ? hbin[t] : 0u;
        for (int d = 1; d < NBIN_MAX; d <<= 1) {
            unsigned x = (t < NBIN_MAX && t >= d) ? hbin[t - d] : 0u;
            __syncthreads();
            if (t < NBIN_MAX) hbin[t] += x;
            __syncthreads();
        }
        if (t < NBIN_MAX) curbin[t] = (unsigned)ebeg + hbin[t] - v;
    }
    __syncthreads();
    if (t < NBIN) s1addr[(size_t)t * EB + b] = curbin[t];
    if (t == 0)  s1addr[(size_t)NBIN * EB + b] = (unsigned)eend;
    __syncthreads();

    for (long long e = ebeg + t; e < eend; e += CTHR) {
        int nf = __builtin_nontemporal_load(&nfrom[e]);
        int nt = __builtin_nontemporal_load(&nto[e]);
        float l  = __builtin_nontemporal_load(&elen[e]);
        float ex = __builtin_nontemporal_load(&evec[e * 3 + 0]);
        float ey = __builtin_nontemporal_load(&evec[e * 3 + 1]);
        float ez = __builtin_nontemporal_load(&evec[e * 3 + 2]);
        unsigned bin = ((unsigned)nt) >> BINB;
        unsigned pos = atomicAdd(&curbin[bin], 1u);
        U32H2 a, c;
        a.h = __floats2half2_rn(l, ex);
        c.h = __floats2half2_rn(ey, ez);
        rec12 r;
        r.x = (unsigned)nf | (((unsigned)nt & ((1u << BINB) - 1u)) << 18);
        r.y = a.u;
        r.z = c.u;
        payA[pos] = r;
    }
}

// Column sums of s1addr rows -> binsum[q] (q = 0..NBIN). EB==512, 256 thr: 2 each.
__global__ __launch_bounds__(256) void colsum_kernel(
    const unsigned* __restrict__ s1addr, unsigned* __restrict__ binsum)
{
    __shared__ unsigned red[256];
    int q = blockIdx.x, t = threadIdx.x;
    red[t] = s1addr[(size_t)q * EB + t] + s1addr[(size_t)q * EB + t + 256];
    __syncthreads();
    for (int d = 128; d > 0; d >>= 1) {
        if (t < d) red[t] += red[t + d];
        __syncthreads();
    }
    if (t == 0) binsum[q] = red[0];
}

// binstart[q] = binsum[q] - binsum[0]  (since s1addr[0][b] = chunk start).
// Also writes the nodestart sentinel at NBIN<<BINB.
__global__ __launch_bounds__(256) void binstart_kernel(
    const unsigned* __restrict__ binsum, unsigned* __restrict__ binstart,
    unsigned* __restrict__ nodestart, int NBIN, int E)
{
    int t = threadIdx.x;
    unsigned b0 = binsum[0];
    for (int q = t; q <= NBIN; q += 256) binstart[q] = binsum[q] - b0;
    if (t == 0) nodestart[(size_t)NBIN << BINB] = (unsigned)E;
}

// Pass 2: one block per bin (1024 nodes). (A) histogram nt&1023 over the bin's
// 512 segments (binary search on the LDS segment table), (B) LDS-scan -> cursors
// (+ nodestart CSR emit), then place records FULLY nt-sorted into a contiguous
// window of dst. Gathers: cf = coords4[nf] (random, L2-resident 3.2MB table,
// 2-deep pipeline), ct = coords4[nt] (4KB bin window, L1). Computes g2, g3; g1
// arrives as cf.w. Output record (12B): x = nf | (nt&63)<<18, y = h2(g0,g1),
// z = h2(g2,g3).
__global__ __launch_bounds__(CTHR) void pass2_kernel(
    const unsigned* __restrict__ s1addr,
    const unsigned* __restrict__ binstart,
    const float4* __restrict__ coords4,
    const rec12* __restrict__ src,
    rec12* __restrict__ dst,
    unsigned* __restrict__ nodestart,
    int NBIN)
{
    __shared__ unsigned segst[EB];        // 2 KB
    __shared__ unsigned spref[EB + 1];    // 2 KB
    __shared__ unsigned hist[1 << BINB];  // 4 KB
    __shared__ unsigned cur[1 << BINB];   // 4 KB
    int q = blockIdx.x, t = threadIdx.x;

    if (t < EB) {
        unsigned st = s1addr[(size_t)q * EB + t];
        unsigned en = s1addr[(size_t)(q + 1) * EB + t];
        segst[t] = st;
        spref[t] = en - st;
    }
    hist[t] = 0;
    __syncthreads();
    {   // exclusive scan of the 512 segment lengths
        unsigned v = (t < EB) ? spref[t] : 0u;
        for (int d = 1; d < EB; d <<= 1) {
            unsigned x = (t < EB && t >= d) ? spref[t - d] : 0u;
            __syncthreads();
            if (t < EB) spref[t] += x;
            __syncthreads();
        }
        unsigned incl = (t < EB) ? spref[t] : 0u;
        __syncthreads();
        if (t < EB) spref[t] = incl - v;
        if (t == EB - 1) spref[EB] = incl;
    }
    __syncthreads();
    unsigned len = spref[EB];
    unsigned obase = binstart[q];
    const unsigned* srcw = (const unsigned*)src;

    // pass A: histogram keys (reads only word0 of each 12B record)
    for (unsigned i = t; i < len; i += CTHR) {
        unsigned lo = 0, hi = EB;
#pragma unroll
        for (int s = 0; s < 9; s++) {
            unsigned mid = (lo + hi) >> 1;
            if (spref[mid] <= i) lo = mid; else hi = mid;
        }
        unsigned x0 = srcw[(size_t)(segst[lo] + (i - spref[lo])) * 3];
        atomicAdd(&hist[(x0 >> 18) & ((1u << BINB) - 1u)], 1u);
    }
    __syncthreads();
    // scan 1024-key histogram (inclusive, in place), 1024 threads
    unsigned hv = hist[t];
    __syncthreads();
    for (int d = 1; d < (1 << BINB); d <<= 1) {
        unsigned x = (t >= d) ? hist[t - d] : 0u;
        __syncthreads();
        hist[t] += x;
        __syncthreads();
    }
    unsigned excl = hist[t] - hv;
    cur[t] = obase + excl;
    nodestart[((size_t)q << BINB) + t] = obase + excl;   // node-level CSR
    __syncthreads();

    // pass B: place nt-sorted; 2-deep pipeline hides the cf gather latency
    rec12 p0; float4 cf0;
    {
        unsigned i0 = t;
        if (i0 < len) {
            unsigned lo = 0, hi = EB;
#pragma unroll
            for (int s = 0; s < 9; s++) {
                unsigned mid = (lo + hi) >> 1;
                if (spref[mid] <= i0) lo = mid; else hi = mid;
            }
            p0 = src[segst[lo] + (i0 - spref[lo])];
            cf0 = coords4[p0.x & 0x3FFFFu];
        }
    }
    for (unsigned i = t; i < len; i += CTHR) {
        unsigned i1 = i + CTHR;
        rec12 p1 = p0; float4 cf1 = cf0;
        if (i1 < len) {
            unsigned lo = 0, hi = EB;
#pragma unroll
            for (int s = 0; s < 9; s++) {
                unsigned mid = (lo + hi) >> 1;
                if (spref[mid] <= i1) lo = mid; else hi = mid;
            }
            p1 = src[segst[lo] + (i1 - spref[lo])];
            cf1 = coords4[p1.x & 0x3FFFFu];
        }
        unsigned key = (p0.x >> 18) & ((1u << BINB) - 1u);
        unsigned pos = atomicAdd(&cur[key], 1u);
        unsigned nt = ((unsigned)q << BINB) | key;
        float4 ct = coords4[nt];
        U32H2 ya, za;
        ya.u = p0.y; za.u = p0.z;
        float g0 = __low2float(ya.h), ev0 = __high2float(ya.h);
        float ev1 = __low2float(za.h), ev2 = __high2float(za.h);
        float g2 = cf0.x * ct.x + cf0.y * ct.y + cf0.z * ct.z;
        float g3 = cf0.x * ev0 + cf0.y * ev1 + cf0.z * ev2;
        U32H2 oy, oz;
        oy.h = __floats2half2_rn(g0, cf0.w);
        oz.h = __floats2half2_rn(g2, g3);
        rec12 r;
        r.x = (p0.x & 0x3FFFFu) | ((nt & (BSZ - 1u)) << 18);
        r.y = oy.u;
        r.z = oz.u;
        dst[pos] = r;
        p0 = p1; cf0 = cf1;
    }
}

// ===================== rounds =====================

// wsth[n][j] = fp16( bm[j] + sum_k state[n][k] * Wm[k][j] ), dense 20B rows (4MB total)
__global__ __launch_bounds__(256) void wstate_kernel(
    const float* __restrict__ state, const float* __restrict__ Wm,
    const float* __restrict__ bm, __half* __restrict__ wsth, int N)
{
    int n = blockIdx.x * blockDim.x + threadIdx.x;
    if (n >= N) return;
    const float2* sp = (const float2*)(state + (size_t)n * SD);
    float s[SD];
#pragma unroll
    for (int h = 0; h < 5; h++) { float2 v = sp[h]; s[2*h] = v.x; s[2*h+1] = v.y; }
    float t[SD];
#pragma unroll
    for (int j = 0; j < SD; j++) t[j] = bm[j];
#pragma unroll
    for (int k = 0; k < SD; k++) {
#pragma unroll
        for (int j = 0; j < SD; j++) t[j] += s[k] * Wm[k * SD + j];
    }
    unsigned* dp = (unsigned*)(wsth + (size_t)n * SD);   // 20B rows, 4B aligned
#pragma unroll
    for (int h = 0; h < 5; h++) {
        U32H2 cv;
        cv.h = __floats2half2_rn(t[2*h], t[2*h+1]);
        dp[h] = cv.u;
    }
}

// Run-accumulating round kernel: BSZ=64 -> grid ~3125, high occupancy. Payload
// FULLY nt-sorted (runs ~32/node) -> LDS atomic only on run change. 12B records.
template <bool FIRST>
__global__ __launch_bounds__(256) void round_run_kernel(
    const unsigned* __restrict__ nodestart,
    const rec12* __restrict__ payload,
    const float* __restrict__ Wm,
    const float* __restrict__ bm,
    const __half* __restrict__ wsth,      // (N,10) dense fp16, incl bias
    const float* __restrict__ state_prev,
    float* __restrict__ state_next,
    int N, int E)
{
    __shared__ float acc[BSZ * SD];       // 2.56 KB
    int k = blockIdx.x;
    for (int i = threadIdx.x; i < BSZ * SD; i += 256) acc[i] = 0.0f;

    int lane = threadIdx.x & 63;
    int wv = threadIdx.x >> 6;            // 0..3
    int grp0 = lane / 10;
    bool active = grp0 < 6;
    int grp = active ? grp0 : 5;
    int j = active ? (lane - grp0 * 10) : (lane - 60);

    float w0 = Wm[10 * SD + j];
    float w1 = Wm[11 * SD + j];
    float w2 = Wm[12 * SD + j];
    float w3 = Wm[13 * SD + j];
    float bb = bm[j];
    __syncthreads();

    unsigned beg = nodestart[(size_t)k << 6];
    unsigned end = nodestart[(size_t)(k + 1) << 6];
    unsigned len = end - beg;
    unsigned Q = (len + 3) >> 2;
    unsigned rbeg = beg + (unsigned)wv * Q;
    unsigned rend = rbeg + Q; if (rend > end) rend = end;
    unsigned eclamp = (unsigned)E - 1u;

    // pipeline preload: payload depth 2, wst depth 1
    unsigned e0 = rbeg + (unsigned)grp;
    rec12 P0 = payload[e0 <= eclamp ? e0 : eclamp];
    unsigned e1 = e0 + 6;
    rec12 P1 = payload[e1 <= eclamp ? e1 : eclamp];
    float T0 = bb, T1 = bb;
    if (!FIRST) T0 = __half2float(wsth[(size_t)(P0.x & 0x3FFFFu) * SD + j]);

    int cur_lnt = -1;
    float accv = 0.0f;

    for (unsigned base = rbeg; base < rend; base += 6) {
        unsigned e2 = base + 12 + (unsigned)grp;
        rec12 P2 = payload[e2 <= eclamp ? e2 : eclamp];
        if (!FIRST) T1 = __half2float(wsth[(size_t)(P1.x & 0x3FFFFu) * SD + j]);
        unsigned e = base + (unsigned)grp;
        if (active && e < rend) {
            int lnt = (int)((P0.x >> 18) & (BSZ - 1));
            U32H2 c01, c23;
            c01.u = P0.y; c23.u = P0.z;
            float g0 = __low2float(c01.h), g1 = __high2float(c01.h);
            float g2 = __low2float(c23.h), g3 = __high2float(c23.h);
            float t = T0 + g0 * w0 + g1 * w1 + g2 * w2 + g3 * w3;
            if (lnt != cur_lnt) {
                if (cur_lnt >= 0) atomicAdd(&acc[cur_lnt * SD + j], accv);
                accv = 0.0f;
                cur_lnt = lnt;
            }
            accv += tanh_fast(t);
        }
        P0 = P1; P1 = P2; T0 = T1;
    }
    if (active && cur_lnt >= 0) atomicAdd(&acc[cur_lnt * SD + j], accv);
    __syncthreads();

    int base_o = k * BSZ * SD;
    int lim = N * SD - base_o;
    for (int i = threadIdx.x; i < BSZ * SD; i += 256) {
        if (i < lim) {
            float v = acc[i];
            if (!FIRST) v += state_prev[base_o + i];
            state_next[base_o + i] = v;
        }
    }
}

// ===================== graph phase =====================

__global__ __launch_bounds__(256) void goff_kernel(
    const int* __restrict__ gidx, unsigned* __restrict__ goff, int N, int G)
{
    int n = blockIdx.x * blockDim.x + threadIdx.x;
    if (n >= N) return;
    int g = gidx[n];
    if (n == 0) {
        for (int q = 0; q <= g; q++) goff[q] = 0;
    } else {
        int gp = gidx[n - 1];
        for (int q = gp + 1; q <= g; q++) goff[q] = (unsigned)n;
    }
    if (n == N - 1) {
        for (int q = g + 1; q <= G; q++) goff[q] = (unsigned)N;
    }
}

// 4-way split per (g,j); one atomic per partial. gstate must be zeroed.
__global__ __launch_bounds__(256) void gsum_kernel(
    const float* __restrict__ state, const unsigned* __restrict__ goff,
    float* __restrict__ gstate, int G)
{
    int tid = blockIdx.x * blockDim.x + threadIdx.x;
    if (tid >= G * SD * 4) return;
    int s = tid & 3;
    int rest = tid >> 2;
    int g = rest / SD;
    int j = rest - g * SD;
    unsigned beg = goff[g], end = goff[g + 1];
    unsigned len = end - beg;
    unsigned b0 = beg + (len * (unsigned)s) / 4u;
    unsigned b1 = beg + (len * (unsigned)(s + 1)) / 4u;
    float a = 0.0f;
    for (unsigned n = b0; n < b1; n++) a += state[(size_t)n * SD + j];
    atomicAdd(&gstate[(size_t)g * SD + j], a);
}

__global__ __launch_bounds__(256) void out_kernel(
    const float* __restrict__ gstate, const float* __restrict__ Wo,
    const float* __restrict__ bo, float* __restrict__ out, int G)
{
    int g = blockIdx.x * blockDim.x + threadIdx.x;
    if (g >= G) return;
    float s[SD];
#pragma unroll
    for (int k = 0; k < SD; k++) s[k] = gstate[(size_t)g * SD + k];
    float ev[4];
#pragma unroll
    for (int c = 0; c < 4; c++) {
        float a = bo[c];
#pragma unroll
        for (int k = 0; k < SD; k++) a += s[k] * Wo[k * 4 + c];
        ev[c] = a;
    }
    out[g * 4 + 0] = ev[0];
    out[g * 4 + 1] = softplus_f(ev[1]);
    out[g * 4 + 2] = softplus_f(ev[2]) + 1.0f;
    out[g * 4 + 3] = softplus_f(ev[3]);
}

// ===================== fallback (atomic path) =====================

template <bool FIRST>
__global__ __launch_bounds__(256) void edge_kernel_fb(
    const float* __restrict__ coords, const float* __restrict__ elen,
    const float* __restrict__ evec, const float* __restrict__ Wm,
    const float* __restrict__ bm, const int* __restrict__ nfrom,
    const int* __restrict__ nto, const float* __restrict__ state_prev,
    float* __restrict__ state_next, int E)
{
    int e = blockIdx.x * blockDim.x + threadIdx.x;
    if (e >= E) return;
    int nf = nfrom[e];
    int nt = nto[e];
    float cf0 = coords[nf*3+0], cf1 = coords[nf*3+1], cf2 = coords[nf*3+2];
    float ct0 = coords[nt*3+0], ct1 = coords[nt*3+1], ct2 = coords[nt*3+2];
    float ev0 = evec[e*3+0], ev1 = evec[e*3+1], ev2 = evec[e*3+2];
    float g0 = elen[e];
    float g1 = fabsf(cf0) + fabsf(cf1) + fabsf(cf2);
    float g2 = cf0*ct0 + cf1*ct1 + cf2*ct2;
    float g3 = cf0*ev0 + cf1*ev1 + cf2*ev2;
    float acc[SD];
#pragma unroll
    for (int j = 0; j < SD; j++) {
        acc[j] = bm[j] + g0*Wm[10*SD+j] + g1*Wm[11*SD+j] + g2*Wm[12*SD+j] + g3*Wm[13*SD+j];
    }
    if (!FIRST) {
        const float2* sp = (const float2*)(state_prev + (size_t)nf * SD);
        float s[SD];
#pragma unroll
        for (int h = 0; h < 5; h++) { float2 v = sp[h]; s[2*h] = v.x; s[2*h+1] = v.y; }
#pragma unroll
        for (int k = 0; k < SD; k++) {
#pragma unroll
            for (int j = 0; j < SD; j++) acc[j] += s[k] * Wm[k*SD+j];
        }
    }
    float* dst = state_next + (size_t)nt * SD;
#pragma unroll
    for (int j = 0; j < SD; j++) atomicAdd(dst + j, tanh_fast(acc[j]));
}

__global__ __launch_bounds__(256) void graph_reduce_fb(
    const float* __restrict__ state, const int* __restrict__ gidx,
    float* __restrict__ gstate, int N)
{
    int n = blockIdx.x * blockDim.x + threadIdx.x;
    if (n >= N) return;
    int g = gidx[n];
    const float2* sp = (const float2*)(state + (size_t)n * SD);
    float* dst = gstate + (size_t)g * SD;
#pragma unroll
    for (int h = 0; h < 5; h++) {
        float2 v = sp[h];
        atomicAdd(dst + 2*h, v.x);
        atomicAdd(dst + 2*h + 1, v.y);
    }
}

// ===================== launch =====================

extern "C" void kernel_launch(void* const* d_in, const int* in_sizes, int n_in,
                              void* d_out, int out_size, void* d_ws, size_t ws_size,
                              hipStream_t stream) {
    const float* coords = (const float*)d_in[0];
    const float* elen   = (const float*)d_in[1];
    const float* evec   = (const float*)d_in[2];
    const float* Wm     = (const float*)d_in[3];
    const float* bm     = (const float*)d_in[4];
    const float* Wo     = (const float*)d_in[5];
    const float* bo     = (const float*)d_in[6];
    const int* nfrom    = (const int*)d_in[7];
    const int* nto      = (const int*)d_in[8];
    const int* gidx     = (const int*)d_in[9];

    const int E = in_sizes[1];
    const int N = in_sizes[9];
    const int G = out_size / 4;

    const int NBIN = (N + (1 << BINB) - 1) >> BINB;   // bins (<= 256)
    const int NB   = (N + BSZ - 1) / BSZ;             // round buckets (~3125)

    const int BLK = 256;
    const int ng = (N + BLK - 1) / BLK;
    const int gg = (G + BLK - 1) / BLK;

    auto align256 = [](size_t x) { return (x + 255) & ~(size_t)255; };
    const size_t state_bytes = align256((size_t)N * SD * sizeof(float));
    const size_t wst_bytes   = align256((size_t)N * SD * sizeof(__half) + 256);
    const size_t payA_bytes  = align256((size_t)E * sizeof(rec12) + 256);
    const size_t payB_bytes  = align256((size_t)E * sizeof(rec12) + 256);
    const size_t s1a_bytes   = align256((size_t)(NBIN_MAX + 1) * EB * sizeof(unsigned));
    const size_t bsum_bytes  = align256((size_t)(NBIN_MAX + 1) * sizeof(unsigned));
    const size_t nst_bytes   = align256(((size_t)NBIN_MAX * (1 << BINB) + 2) * sizeof(unsigned));
    const size_t goff_bytes  = align256((size_t)(G + 1) * sizeof(unsigned));
    const size_t gst_bytes   = align256((size_t)G * SD * sizeof(float));
    const size_t c4_bytes    = align256((size_t)N * sizeof(float4));

    size_t o = 0;
    char* w = (char*)d_ws;
    float* stateA      = (float*)(w + o);    o += state_bytes;
    float* stateB      = (float*)(w + o);    o += state_bytes;
    __half* wsth       = (__half*)(w + o);   o += wst_bytes;
    rec12* payA        = (rec12*)(w + o);    o += payA_bytes;   // bin-sorted block-major
    rec12* payB        = (rec12*)(w + o);    o += payB_bytes;   // fully nt-sorted
    unsigned* s1addr   = (unsigned*)(w + o); o += s1a_bytes;
    unsigned* binsum   = (unsigned*)(w + o); o += bsum_bytes;
    unsigned* binstart = (unsigned*)(w + o); o += bsum_bytes;
    unsigned* nodestart= (unsigned*)(w + o); o += nst_bytes;
    unsigned* goff     = (unsigned*)(w + o); o += goff_bytes;
    float* gstate      = (float*)(w + o);    o += gst_bytes;
    float4* coords4    = (float4*)(w + o);   o += c4_bytes;

    if (o <= ws_size && NBIN <= NBIN_MAX && N < (1 << 18)) {
        // ---- prep + build ----
        coords4_kernel<<<ng, BLK, 0, stream>>>(coords, coords4, N);
        pass1_kernel<<<EB, CTHR, 0, stream>>>(elen, evec, nfrom, nto,
                                              s1addr, payA, E, NBIN);
        colsum_kernel<<<NBIN + 1, 256, 0, stream>>>(s1addr, binsum);
        binstart_kernel<<<1, 256, 0, stream>>>(binsum, binstart, nodestart, NBIN, E);
        pass2_kernel<<<NBIN, CTHR, 0, stream>>>(s1addr, binstart, coords4,
                                                payA, payB, nodestart, NBIN);
        // ---- rounds (sorted 12B payload, high-occupancy 64-node buckets) ----
        round_run_kernel<true><<<NB, BLK, 0, stream>>>(nodestart, payB, Wm, bm,
                                                       wsth, stateB, stateA, N, E);
        wstate_kernel<<<ng, BLK, 0, stream>>>(stateA, Wm, bm, wsth, N);
        round_run_kernel<false><<<NB, BLK, 0, stream>>>(nodestart, payB, Wm, bm,
                                                        wsth, stateA, stateB, N, E);
        wstate_kernel<<<ng, BLK, 0, stream>>>(stateB, Wm, bm, wsth, N);
        round_run_kernel<false><<<NB, BLK, 0, stream>>>(nodestart, payB, Wm, bm,
                                                        wsth, stateB, stateA, N, E);
        // ---- graph phase ----
        hipMemsetAsync(gstate, 0, (size_t)G * SD * sizeof(float), stream);
        goff_kernel<<<ng, BLK, 0, stream>>>(gidx, goff, N, G);
        gsum_kernel<<<(G * SD * 4 + BLK - 1) / BLK, BLK, 0, stream>>>(stateA, goff, gstate, G);
        out_kernel<<<gg, BLK, 0, stream>>>(gstate, Wo, bo, (float*)d_out, G);
    } else {
        // ---- fallback: atomic path ----
        const int eg = (E + BLK - 1) / BLK;
        float* gstateF = (float*)(w + 2 * state_bytes);
        hipMemsetAsync(stateA, 0, state_bytes, stream);
        hipMemsetAsync(gstateF, 0, (size_t)G * SD * sizeof(float), stream);
        edge_kernel_fb<true><<<eg, BLK, 0, stream>>>(coords, elen, evec, Wm, bm,
                                                     nfrom, nto, stateA, stateA, E);
        hipMemcpyAsync(stateB, stateA, state_bytes, hipMemcpyDeviceToDevice, stream);
        edge_kernel_fb<false><<<eg, BLK, 0, stream>>>(coords, elen, evec, Wm, bm,
                                                      nfrom, nto, stateA, stateB, E);
        hipMemcpyAsync(stateA, stateB, state_bytes, hipMemcpyDeviceToDevice, stream);
        edge_kernel_fb<false><<<eg, BLK, 0, stream>>>(coords, elen, evec, Wm, bm,
                                                      nfrom, nto, stateB, stateA, E);
        graph_reduce_fb<<<ng, BLK, 0, stream>>>(stateA, gidx, gstateF, N);
        out_kernel<<<gg, BLK, 0, stream>>>(gstateF, Wo, bo, (float*)d_out, G);
    }
}

// Round 8
// 679.978 us; speedup vs baseline: 2.5087x; 1.0328x over previous
//
#include <hip/hip_runtime.h>
#include <hip/hip_fp16.h>
#include <math.h>

#define SD 10
#define BSZ 64                // round-kernel bucket (nodes per round block)
#define EB 512                // edge-chunk blocks (pass-1 grid)
#define CTHR 1024             // threads for pass1/pass2
#define BINB 9                // bin bits: 512 nodes per bin
#define NBIN_MAX 512          // N <= 512*512 = 262144 (and N < 2^18 gate)
#define HSZ 256               // pass-2 half size (nodes per staged sub-pass)
#define SCAP 10880            // LDS staging capacity (records); avg half = 8192

typedef unsigned uvec4 __attribute__((ext_vector_type(4)));
struct rec12 { unsigned x, y, z; };   // 12B packed payload
union U32H2 { unsigned u; __half2 h; };

__device__ __forceinline__ float tanh_fast(float x) {
    float e = __expf(2.0f * x);
    float r = __builtin_amdgcn_rcpf(1.0f + e);
    return 1.0f - 2.0f * r;
}

__device__ __forceinline__ float softplus_f(float x) {
    return fmaxf(x, 0.0f) + log1pf(expf(-fabsf(x)));
}

// ===================== prep =====================

// coords4[n] = {x, y, z, g1=|x|+|y|+|z|}: g1 rides along with every cf gather.
__global__ __launch_bounds__(256) void coords4_kernel(
    const float* __restrict__ coords, float4* __restrict__ coords4, int N)
{
    int n = blockIdx.x * blockDim.x + threadIdx.x;
    if (n >= N) return;
    float4 c;
    c.x = coords[n * 3 + 0];
    c.y = coords[n * 3 + 1];
    c.z = coords[n * 3 + 2];
    c.w = fabsf(c.x) + fabsf(c.y) + fabsf(c.z);
    coords4[n] = c;
}

// ===================== build: 2-pass radix with full nt-sort =====================
// Frontier invariant (rounds 0-7 lesson): partial 128B write lines alive at once
// must fit in L2. pass1: 391 streaming bin targets, NT input loads keep L2 clean.
// pass2: sorted output is staged in LDS and streamed out as FULL lines -- the
// global memory never sees a partial-line scatter.

// Pass 1: block b splits its chunk [ebeg,eend) by 512-node bin, contiguous emit.
// Record: x = nf | (nt&511)<<18 ; y = h2(elen, ev0) ; z = h2(ev1, ev2).
// Emits s1addr[bin][b] = segment start; sentinel row s1addr[NBIN][b] = chunk end.
__global__ __launch_bounds__(CTHR) void pass1_kernel(
    const float* __restrict__ elen,
    const float* __restrict__ evec,
    const int* __restrict__ nfrom,
    const int* __restrict__ nto,
    unsigned* __restrict__ s1addr,
    rec12* __restrict__ payA,
    int E, int NBIN)
{
    __shared__ unsigned hbin[NBIN_MAX];
    __shared__ unsigned curbin[NBIN_MAX];
    int b = blockIdx.x, t = threadIdx.x;
    long long ebeg = (long long)E * b / EB;
    long long eend = (long long)E * (b + 1) / EB;

    if (t < NBIN_MAX) hbin[t] = 0;
    __syncthreads();
    for (long long e = ebeg + t; e < eend; e += CTHR)
        atomicAdd(&hbin[((unsigned)__builtin_nontemporal_load(&nto[e])) >> BINB], 1u);
    __syncthreads();
    {   // exclusive scan of hbin -> curbin (lanes t < NBIN_MAX)
        unsigned v = (t < NBIN_MAX) ? hbin[t] : 0u;
        for (int d = 1; d < NBIN_MAX; d <<= 1) {
            unsigned x = (t < NBIN_MAX && t >= d) ? hbin[t - d] : 0u;
            __syncthreads();
            if (t < NBIN_MAX) hbin[t] += x;
            __syncthreads();
        }
        if (t < NBIN_MAX) curbin[t] = (unsigned)ebeg + hbin[t] - v;
    }
    __syncthreads();
    if (t < NBIN) s1addr[(size_t)t * EB + b] = curbin[t];
    if (t == 0)  s1addr[(size_t)NBIN * EB + b] = (unsigned)eend;
    __syncthreads();

    for (long long e = ebeg + t; e < eend; e += CTHR) {
        int nf = __builtin_nontemporal_load(&nfrom[e]);
        int nt = __builtin_nontemporal_load(&nto[e]);
        float l  = __builtin_nontemporal_load(&elen[e]);
        float ex = __builtin_nontemporal_load(&evec[e * 3 + 0]);
        float ey = __builtin_nontemporal_load(&evec[e * 3 + 1]);
        float ez = __builtin_nontemporal_load(&evec[e * 3 + 2]);
        unsigned bin = ((unsigned)nt) >> BINB;
        unsigned pos = atomicAdd(&curbin[bin], 1u);
        U32H2 a, c;
        a.h = __floats2half2_rn(l, ex);
        c.h = __floats2half2_rn(ey, ez);
        rec12 r;
        r.x = (unsigned)nf | (((unsigned)nt & ((1u << BINB) - 1u)) << 18);
        r.y = a.u;
        r.z = c.u;
        payA[pos] = r;
    }
}

// Column sums of s1addr rows -> binsum[q] (q = 0..NBIN). EB==512, 256 thr: 2 each.
__global__ __launch_bounds__(256) void colsum_kernel(
    const unsigned* __restrict__ s1addr, unsigned* __restrict__ binsum)
{
    __shared__ unsigned red[256];
    int q = blockIdx.x, t = threadIdx.x;
    red[t] = s1addr[(size_t)q * EB + t] + s1addr[(size_t)q * EB + t + 256];
    __syncthreads();
    for (int d = 128; d > 0; d >>= 1) {
        if (t < d) red[t] += red[t + d];
        __syncthreads();
    }
    if (t == 0) binsum[q] = red[0];
}

// binstart[q] = binsum[q] - binsum[0]  (since s1addr[0][b] = chunk start).
// Also writes the nodestart sentinel at NBIN<<BINB.
__global__ __launch_bounds__(256) void binstart_kernel(
    const unsigned* __restrict__ binsum, unsigned* __restrict__ binstart,
    unsigned* __restrict__ nodestart, int NBIN, int E)
{
    int t = threadIdx.x;
    unsigned b0 = binsum[0];
    for (int q = t; q <= NBIN; q += 256) binstart[q] = binsum[q] - b0;
    if (t == 0) nodestart[(size_t)NBIN << BINB] = (unsigned)E;
}

// Pass 2: one block per bin (512 nodes). Histogram (1 read, warms L2) -> scan ->
// cursors + node CSR. Then TWO half-passes (256 nodes each): re-scan the bin
// (L2-hit), scatter matching records into a 130KB LDS staging buffer via LDS
// cursors, barrier, stream LDS -> dst as contiguous FULL-LINE writes, computing
// features during streamout (ct gather is nt-sorted -> L1 sequential; cf gather
// hidden by a 2-deep pipeline). Oversized halves (never statistically) fall back
// to direct scatter -- still correct.
__global__ __launch_bounds__(CTHR) void pass2_kernel(
    const unsigned* __restrict__ s1addr,
    const unsigned* __restrict__ binstart,
    const float4* __restrict__ coords4,
    const rec12* __restrict__ src,
    rec12* __restrict__ dst,
    unsigned* __restrict__ nodestart,
    int NBIN)
{
    __shared__ unsigned segst[EB];          // 2 KB
    __shared__ unsigned spref[EB + 1];      // 2 KB
    __shared__ unsigned hist[1 << BINB];    // 2 KB
    __shared__ unsigned cur[1 << BINB];     // 2 KB
    __shared__ rec12 stage[SCAP];           // 130.6 KB
    int q = blockIdx.x, t = threadIdx.x;
    const unsigned KMASK = (1u << BINB) - 1u;

    if (t < EB) {
        unsigned st = s1addr[(size_t)q * EB + t];
        unsigned en = s1addr[(size_t)(q + 1) * EB + t];
        segst[t] = st;
        spref[t] = en - st;
    }
    if (t < (1 << BINB)) hist[t] = 0;
    __syncthreads();
    {   // exclusive scan of the 512 segment lengths
        unsigned v = (t < EB) ? spref[t] : 0u;
        for (int d = 1; d < EB; d <<= 1) {
            unsigned x = (t < EB && t >= d) ? spref[t - d] : 0u;
            __syncthreads();
            if (t < EB) spref[t] += x;
            __syncthreads();
        }
        unsigned incl = (t < EB) ? spref[t] : 0u;
        __syncthreads();
        if (t < EB) spref[t] = incl - v;
        if (t == EB - 1) spref[EB] = incl;
    }
    __syncthreads();
    unsigned len = spref[EB];
    unsigned obase = binstart[q];
    const unsigned* srcw = (const unsigned*)src;

    // histogram pass (reads word0; whole lines pulled -> warms L2 for re-reads)
    for (unsigned i = t; i < len; i += CTHR) {
        unsigned lo = 0, hi = EB;
#pragma unroll
        for (int s = 0; s < 9; s++) {
            unsigned mid = (lo + hi) >> 1;
            if (spref[mid] <= i) lo = mid; else hi = mid;
        }
        unsigned x0 = srcw[(size_t)(segst[lo] + (i - spref[lo])) * 3];
        atomicAdd(&hist[(x0 >> 18) & KMASK], 1u);
    }
    __syncthreads();
    // inclusive scan of 512-key histogram (kept inclusive: half bounds read it)
    unsigned hv = (t < (1 << BINB)) ? hist[t] : 0u;
    __syncthreads();
    for (int d = 1; d < (1 << BINB); d <<= 1) {
        unsigned x = (t < (1 << BINB) && t >= d) ? hist[t - d] : 0u;
        __syncthreads();
        if (t < (1 << BINB)) hist[t] += x;
        __syncthreads();
    }
    if (t < (1 << BINB)) {
        unsigned excl = hist[t] - hv;
        cur[t] = obase + excl;
        nodestart[((size_t)q << BINB) + t] = obase + excl;   // node-level CSR
    }
    __syncthreads();

    for (int h = 0; h < (1 << BINB) / HSZ; ++h) {
        unsigned kbeg = (unsigned)h * HSZ, kend = kbeg + HSZ;
        unsigned qs = kbeg ? hist[kbeg - 1] : 0u;
        unsigned qe = hist[kend - 1];
        unsigned qlen = qe - qs;
        unsigned qg = obase + qs;                 // global output base of this half
        if (qlen <= (unsigned)SCAP) {
            // scatter into LDS (no global partial lines)
            for (unsigned i = t; i < len; i += CTHR) {
                unsigned lo = 0, hi = EB;
#pragma unroll
                for (int s = 0; s < 9; s++) {
                    unsigned mid = (lo + hi) >> 1;
                    if (spref[mid] <= i) lo = mid; else hi = mid;
                }
                rec12 p = src[segst[lo] + (i - spref[lo])];
                unsigned key = (p.x >> 18) & KMASK;
                if (key >= kbeg && key < kend) {
                    unsigned pos = atomicAdd(&cur[key], 1u);
                    stage[pos - qg] = p;
                }
            }
            __syncthreads();
            // streamout: full-line contiguous writes; features computed here.
            // 2-deep pipeline hides the random cf gather; ct gather is sorted.
            unsigned i = t;
            rec12 p0; float4 cf0;
            if (i < qlen) {
                p0 = stage[i];
                cf0 = coords4[p0.x & 0x3FFFFu];
            }
            while (i < qlen) {
                unsigned i1 = i + CTHR;
                rec12 p1 = p0; float4 cf1 = cf0;
                if (i1 < qlen) {
                    p1 = stage[i1];
                    cf1 = coords4[p1.x & 0x3FFFFu];
                }
                unsigned key = (p0.x >> 18) & KMASK;
                unsigned nf = p0.x & 0x3FFFFu;
                unsigned nt = ((unsigned)q << BINB) | key;
                float4 ct = coords4[nt];
                U32H2 ya, za;
                ya.u = p0.y; za.u = p0.z;
                float g0 = __low2float(ya.h), ev0 = __high2float(ya.h);
                float ev1 = __low2float(za.h), ev2 = __high2float(za.h);
                float g2 = cf0.x * ct.x + cf0.y * ct.y + cf0.z * ct.z;
                float g3 = cf0.x * ev0 + cf0.y * ev1 + cf0.z * ev2;
                U32H2 oy, oz;
                oy.h = __floats2half2_rn(g0, cf0.w);
                oz.h = __floats2half2_rn(g2, g3);
                rec12 r;
                r.x = nf | ((nt & (BSZ - 1u)) << 18);
                r.y = oy.u;
                r.z = oz.u;
                dst[qg + i] = r;
                i = i1; p0 = p1; cf0 = cf1;
            }
            __syncthreads();
        } else {
            // fallback: direct scatter (correct, partial-line cost; ~never taken)
            for (unsigned i = t; i < len; i += CTHR) {
                unsigned lo = 0, hi = EB;
#pragma unroll
                for (int s = 0; s < 9; s++) {
                    unsigned mid = (lo + hi) >> 1;
                    if (spref[mid] <= i) lo = mid; else hi = mid;
                }
                rec12 p = src[segst[lo] + (i - spref[lo])];
                unsigned key = (p.x >> 18) & KMASK;
                if (key >= kbeg && key < kend) {
                    unsigned pos = atomicAdd(&cur[key], 1u);
                    unsigned nf = p.x & 0x3FFFFu;
                    unsigned nt = ((unsigned)q << BINB) | key;
                    float4 cf = coords4[nf];
                    float4 ct = coords4[nt];
                    U32H2 ya, za;
                    ya.u = p.y; za.u = p.z;
                    float g0 = __low2float(ya.h), ev0 = __high2float(ya.h);
                    float ev1 = __low2float(za.h), ev2 = __high2float(za.h);
                    float g2 = cf.x * ct.x + cf.y * ct.y + cf.z * ct.z;
                    float g3 = cf.x * ev0 + cf.y * ev1 + cf.z * ev2;
                    U32H2 oy, oz;
                    oy.h = __floats2half2_rn(g0, cf.w);
                    oz.h = __floats2half2_rn(g2, g3);
                    rec12 r;
                    r.x = nf | ((nt & (BSZ - 1u)) << 18);
                    r.y = oy.u;
                    r.z = oz.u;
                    dst[pos] = r;
                }
            }
            __syncthreads();
        }
    }
}

// ===================== rounds =====================

// wsth[n][j] = fp16( bm[j] + sum_k state[n][k] * Wm[k][j] ), dense 20B rows (4MB total)
__global__ __launch_bounds__(256) void wstate_kernel(
    const float* __restrict__ state, const float* __restrict__ Wm,
    const float* __restrict__ bm, __half* __restrict__ wsth, int N)
{
    int n = blockIdx.x * blockDim.x + threadIdx.x;
    if (n >= N) return;
    const float2* sp = (const float2*)(state + (size_t)n * SD);
    float s[SD];
#pragma unroll
    for (int h = 0; h < 5; h++) { float2 v = sp[h]; s[2*h] = v.x; s[2*h+1] = v.y; }
    float t[SD];
#pragma unroll
    for (int j = 0; j < SD; j++) t[j] = bm[j];
#pragma unroll
    for (int k = 0; k < SD; k++) {
#pragma unroll
        for (int j = 0; j < SD; j++) t[j] += s[k] * Wm[k * SD + j];
    }
    unsigned* dp = (unsigned*)(wsth + (size_t)n * SD);   // 20B rows, 4B aligned
#pragma unroll
    for (int h = 0; h < 5; h++) {
        U32H2 cv;
        cv.h = __floats2half2_rn(t[2*h], t[2*h+1]);
        dp[h] = cv.u;
    }
}

// Run-accumulating round kernel: BSZ=64 -> grid ~3125, high occupancy. Payload
// FULLY nt-sorted (runs ~32/node) -> LDS atomic only on run change. 12B records.
template <bool FIRST>
__global__ __launch_bounds__(256) void round_run_kernel(
    const unsigned* __restrict__ nodestart,
    const rec12* __restrict__ payload,
    const float* __restrict__ Wm,
    const float* __restrict__ bm,
    const __half* __restrict__ wsth,      // (N,10) dense fp16, incl bias
    const float* __restrict__ state_prev,
    float* __restrict__ state_next,
    int N, int E)
{
    __shared__ float acc[BSZ * SD];       // 2.56 KB
    int k = blockIdx.x;
    for (int i = threadIdx.x; i < BSZ * SD; i += 256) acc[i] = 0.0f;

    int lane = threadIdx.x & 63;
    int wv = threadIdx.x >> 6;            // 0..3
    int grp0 = lane / 10;
    bool active = grp0 < 6;
    int grp = active ? grp0 : 5;
    int j = active ? (lane - grp0 * 10) : (lane - 60);

    float w0 = Wm[10 * SD + j];
    float w1 = Wm[11 * SD + j];
    float w2 = Wm[12 * SD + j];
    float w3 = Wm[13 * SD + j];
    float bb = bm[j];
    __syncthreads();

    unsigned beg = nodestart[(size_t)k << 6];
    unsigned end = nodestart[(size_t)(k + 1) << 6];
    unsigned len = end - beg;
    unsigned Q = (len + 3) >> 2;
    unsigned rbeg = beg + (unsigned)wv * Q;
    unsigned rend = rbeg + Q; if (rend > end) rend = end;
    unsigned eclamp = (unsigned)E - 1u;

    // pipeline preload: payload depth 2, wst depth 1
    unsigned e0 = rbeg + (unsigned)grp;
    rec12 P0 = payload[e0 <= eclamp ? e0 : eclamp];
    unsigned e1 = e0 + 6;
    rec12 P1 = payload[e1 <= eclamp ? e1 : eclamp];
    float T0 = bb, T1 = bb;
    if (!FIRST) T0 = __half2float(wsth[(size_t)(P0.x & 0x3FFFFu) * SD + j]);

    int cur_lnt = -1;
    float accv = 0.0f;

    for (unsigned base = rbeg; base < rend; base += 6) {
        unsigned e2 = base + 12 + (unsigned)grp;
        rec12 P2 = payload[e2 <= eclamp ? e2 : eclamp];
        if (!FIRST) T1 = __half2float(wsth[(size_t)(P1.x & 0x3FFFFu) * SD + j]);
        unsigned e = base + (unsigned)grp;
        if (active && e < rend) {
            int lnt = (int)((P0.x >> 18) & (BSZ - 1));
            U32H2 c01, c23;
            c01.u = P0.y; c23.u = P0.z;
            float g0 = __low2float(c01.h), g1 = __high2float(c01.h);
            float g2 = __low2float(c23.h), g3 = __high2float(c23.h);
            float t = T0 + g0 * w0 + g1 * w1 + g2 * w2 + g3 * w3;
            if (lnt != cur_lnt) {
                if (cur_lnt >= 0) atomicAdd(&acc[cur_lnt * SD + j], accv);
                accv = 0.0f;
                cur_lnt = lnt;
            }
            accv += tanh_fast(t);
        }
        P0 = P1; P1 = P2; T0 = T1;
    }
    if (active && cur_lnt >= 0) atomicAdd(&acc[cur_lnt * SD + j], accv);
    __syncthreads();

    int base_o = k * BSZ * SD;
    int lim = N * SD - base_o;
    for (int i = threadIdx.x; i < BSZ * SD; i += 256) {
        if (i < lim) {
            float v = acc[i];
            if (!FIRST) v += state_prev[base_o + i];
            state_next[base_o + i] = v;
        }
    }
}

// ===================== graph phase =====================

__global__ __launch_bounds__(256) void goff_kernel(
    const int* __restrict__ gidx, unsigned* __restrict__ goff, int N, int G)
{
    int n = blockIdx.x * blockDim.x + threadIdx.x;
    if (n >= N) return;
    int g = gidx[n];
    if (n == 0) {
        for (int q = 0; q <= g; q++) goff[q] = 0;
    } else {
        int gp = gidx[n - 1];
        for (int q = gp + 1; q <= g; q++) goff[q] = (unsigned)n;
    }
    if (n == N - 1) {
        for (int q = g + 1; q <= G; q++) goff[q] = (unsigned)N;
    }
}

// 4-way split per (g,j); one atomic per partial. gstate must be zeroed.
__global__ __launch_bounds__(256) void gsum_kernel(
    const float* __restrict__ state, const unsigned* __restrict__ goff,
    float* __restrict__ gstate, int G)
{
    int tid = blockIdx.x * blockDim.x + threadIdx.x;
    if (tid >= G * SD * 4) return;
    int s = tid & 3;
    int rest = tid >> 2;
    int g = rest / SD;
    int j = rest - g * SD;
    unsigned beg = goff[g], end = goff[g + 1];
    unsigned len = end - beg;
    unsigned b0 = beg + (len * (unsigned)s) / 4u;
    unsigned b1 = beg + (len * (unsigned)(s + 1)) / 4u;
    float a = 0.0f;
    for (unsigned n = b0; n < b1; n++) a += state[(size_t)n * SD + j];
    atomicAdd(&gstate[(size_t)g * SD + j], a);
}

__global__ __launch_bounds__(256) void out_kernel(
    const float* __restrict__ gstate, const float* __restrict__ Wo,
    const float* __restrict__ bo, float* __restrict__ out, int G)
{
    int g = blockIdx.x * blockDim.x + threadIdx.x;
    if (g >= G) return;
    float s[SD];
#pragma unroll
    for (int k = 0; k < SD; k++) s[k] = gstate[(size_t)g * SD + k];
    float ev[4];
#pragma unroll
    for (int c = 0; c < 4; c++) {
        float a = bo[c];
#pragma unroll
        for (int k = 0; k < SD; k++) a += s[k] * Wo[k * 4 + c];
        ev[c] = a;
    }
    out[g * 4 + 0] = ev[0];
    out[g * 4 + 1] = softplus_f(ev[1]);
    out[g * 4 + 2] = softplus_f(ev[2]) + 1.0f;
    out[g * 4 + 3] = softplus_f(ev[3]);
}

// ===================== fallback (atomic path) =====================

template <bool FIRST>
__global__ __launch_bounds__(256) void edge_kernel_fb(
    const float* __restrict__ coords, const float* __restrict__ elen,
    const float* __restrict__ evec, const float* __restrict__ Wm,
    const float* __restrict__ bm, const int* __restrict__ nfrom,
    const int* __restrict__ nto, const float* __restrict__ state_prev,
    float* __restrict__ state_next, int E)
{
    int e = blockIdx.x * blockDim.x + threadIdx.x;
    if (e >= E) return;
    int nf = nfrom[e];
    int nt = nto[e];
    float cf0 = coords[nf*3+0], cf1 = coords[nf*3+1], cf2 = coords[nf*3+2];
    float ct0 = coords[nt*3+0], ct1 = coords[nt*3+1], ct2 = coords[nt*3+2];
    float ev0 = evec[e*3+0], ev1 = evec[e*3+1], ev2 = evec[e*3+2];
    float g0 = elen[e];
    float g1 = fabsf(cf0) + fabsf(cf1) + fabsf(cf2);
    float g2 = cf0*ct0 + cf1*ct1 + cf2*ct2;
    float g3 = cf0*ev0 + cf1*ev1 + cf2*ev2;
    float acc[SD];
#pragma unroll
    for (int j = 0; j < SD; j++) {
        acc[j] = bm[j] + g0*Wm[10*SD+j] + g1*Wm[11*SD+j] + g2*Wm[12*SD+j] + g3*Wm[13*SD+j];
    }
    if (!FIRST) {
        const float2* sp = (const float2*)(state_prev + (size_t)nf * SD);
        float s[SD];
#pragma unroll
        for (int h = 0; h < 5; h++) { float2 v = sp[h]; s[2*h] = v.x; s[2*h+1] = v.y; }
#pragma unroll
        for (int k = 0; k < SD; k++) {
#pragma unroll
            for (int j = 0; j < SD; j++) acc[j] += s[k] * Wm[k*SD+j];
        }
    }
    float* dst = state_next + (size_t)nt * SD;
#pragma unroll
    for (int j = 0; j < SD; j++) atomicAdd(dst + j, tanh_fast(acc[j]));
}

__global__ __launch_bounds__(256) void graph_reduce_fb(
    const float* __restrict__ state, const int* __restrict__ gidx,
    float* __restrict__ gstate, int N)
{
    int n = blockIdx.x * blockDim.x + threadIdx.x;
    if (n >= N) return;
    int g = gidx[n];
    const float2* sp = (const float2*)(state + (size_t)n * SD);
    float* dst = gstate + (size_t)g * SD;
#pragma unroll
    for (int h = 0; h < 5; h++) {
        float2 v = sp[h];
        atomicAdd(dst + 2*h, v.x);
        atomicAdd(dst + 2*h + 1, v.y);
    }
}

// ===================== launch =====================

extern "C" void kernel_launch(void* const* d_in, const int* in_sizes, int n_in,
                              void* d_out, int out_size, void* d_ws, size_t ws_size,
                              hipStream_t stream) {
    const float* coords = (const float*)d_in[0];
    const float* elen   = (const float*)d_in[1];
    const float* evec   = (const float*)d_in[2];
    const float* Wm     = (const float*)d_in[3];
    const float* bm     = (const float*)d_in[4];
    const float* Wo     = (const float*)d_in[5];
    const float* bo     = (const float*)d_in[6];
    const int* nfrom    = (const int*)d_in[7];
    const int* nto      = (const int*)d_in[8];
    const int* gidx     = (const int*)d_in[9];

    const int E = in_sizes[1];
    const int N = in_sizes[9];
    const int G = out_size / 4;

    const int NBIN = (N + (1 << BINB) - 1) >> BINB;   // bins (<= 512)
    const int NB   = (N + BSZ - 1) / BSZ;             // round buckets (~3125)

    const int BLK = 256;
    const int ng = (N + BLK - 1) / BLK;
    const int gg = (G + BLK - 1) / BLK;

    auto align256 = [](size_t x) { return (x + 255) & ~(size_t)255; };
    const size_t state_bytes = align256((size_t)N * SD * sizeof(float));
    const size_t wst_bytes   = align256((size_t)N * SD * sizeof(__half) + 256);
    const size_t payA_bytes  = align256((size_t)E * sizeof(rec12) + 256);
    const size_t payB_bytes  = align256((size_t)E * sizeof(rec12) + 256);
    const size_t s1a_bytes   = align256((size_t)(NBIN_MAX + 1) * EB * sizeof(unsigned));
    const size_t bsum_bytes  = align256((size_t)(NBIN_MAX + 1) * sizeof(unsigned));
    const size_t nst_bytes   = align256(((size_t)NBIN_MAX * (1 << BINB) + 2) * sizeof(unsigned));
    const size_t goff_bytes  = align256((size_t)(G + 1) * sizeof(unsigned));
    const size_t gst_bytes   = align256((size_t)G * SD * sizeof(float));
    const size_t c4_bytes    = align256((size_t)N * sizeof(float4));

    size_t o = 0;
    char* w = (char*)d_ws;
    float* stateA      = (float*)(w + o);    o += state_bytes;
    float* stateB      = (float*)(w + o);    o += state_bytes;
    __half* wsth       = (__half*)(w + o);   o += wst_bytes;
    rec12* payA        = (rec12*)(w + o);    o += payA_bytes;   // bin-sorted block-major
    rec12* payB        = (rec12*)(w + o);    o += payB_bytes;   // fully nt-sorted
    unsigned* s1addr   = (unsigned*)(w + o); o += s1a_bytes;
    unsigned* binsum   = (unsigned*)(w + o); o += bsum_bytes;
    unsigned* binstart = (unsigned*)(w + o); o += bsum_bytes;
    unsigned* nodestart= (unsigned*)(w + o); o += nst_bytes;
    unsigned* goff     = (unsigned*)(w + o); o += goff_bytes;
    float* gstate      = (float*)(w + o);    o += gst_bytes;
    float4* coords4    = (float4*)(w + o);   o += c4_bytes;

    if (o <= ws_size && NBIN <= NBIN_MAX && N < (1 << 18)) {
        // ---- prep + build ----
        coords4_kernel<<<ng, BLK, 0, stream>>>(coords, coords4, N);
        pass1_kernel<<<EB, CTHR, 0, stream>>>(elen, evec, nfrom, nto,
                                              s1addr, payA, E, NBIN);
        colsum_kernel<<<NBIN + 1, 256, 0, stream>>>(s1addr, binsum);
        binstart_kernel<<<1, 256, 0, stream>>>(binsum, binstart, nodestart, NBIN, E);
        pass2_kernel<<<NBIN, CTHR, 0, stream>>>(s1addr, binstart, coords4,
                                                payA, payB, nodestart, NBIN);
        // ---- rounds (sorted 12B payload, high-occupancy 64-node buckets) ----
        round_run_kernel<true><<<NB, BLK, 0, stream>>>(nodestart, payB, Wm, bm,
                                                       wsth, stateB, stateA, N, E);
        wstate_kernel<<<ng, BLK, 0, stream>>>(stateA, Wm, bm, wsth, N);
        round_run_kernel<false><<<NB, BLK, 0, stream>>>(nodestart, payB, Wm, bm,
                                                        wsth, stateA, stateB, N, E);
        wstate_kernel<<<ng, BLK, 0, stream>>>(stateB, Wm, bm, wsth, N);
        round_run_kernel<false><<<NB, BLK, 0, stream>>>(nodestart, payB, Wm, bm,
                                                        wsth, stateB, stateA, N, E);
        // ---- graph phase ----
        hipMemsetAsync(gstate, 0, (size_t)G * SD * sizeof(float), stream);
        goff_kernel<<<ng, BLK, 0, stream>>>(gidx, goff, N, G);
        gsum_kernel<<<(G * SD * 4 + BLK - 1) / BLK, BLK, 0, stream>>>(stateA, goff, gstate, G);
        out_kernel<<<gg, BLK, 0, stream>>>(gstate, Wo, bo, (float*)d_out, G);
    } else {
        // ---- fallback: atomic path ----
        const int eg = (E + BLK - 1) / BLK;
        float* gstateF = (float*)(w + 2 * state_bytes);
        hipMemsetAsync(stateA, 0, state_bytes, stream);
        hipMemsetAsync(gstateF, 0, (size_t)G * SD * sizeof(float), stream);
        edge_kernel_fb<true><<<eg, BLK, 0, stream>>>(coords, elen, evec, Wm, bm,
                                                     nfrom, nto, stateA, stateA, E);
        hipMemcpyAsync(stateB, stateA, state_bytes, hipMemcpyDeviceToDevice, stream);
        edge_kernel_fb<false><<<eg, BLK, 0, stream>>>(coords, elen, evec, Wm, bm,
                                                      nfrom, nto, stateA, stateB, E);
        hipMemcpyAsync(stateA, stateB, state_bytes, hipMemcpyDeviceToDevice, stream);
        edge_kernel_fb<false><<<eg, BLK, 0, stream>>>(coords, elen, evec, Wm, bm,
                                                      nfrom, nto, stateB, stateA, E);
        graph_reduce_fb<<<ng, BLK, 0, stream>>>(stateA, gidx, gstateF, N);
        out_kernel<<<gg, BLK, 0, stream>>>(gstateF, Wo, bo, (float*)d_out, G);
    }
}

// Round 9
// 670.143 us; speedup vs baseline: 2.5455x; 1.0147x over previous
//
#include <hip/hip_runtime.h>
#include <hip/hip_fp16.h>
#include <math.h>

#define SD 10
#define BSZ 64                // round-kernel bucket (nodes per round block)
#define EB 256                // edge-chunk blocks (pass-1 grid): <=32/XCD resident
#define CTHR 1024             // threads for pass1/pass2
#define BINB 8                // bin bits: 256 nodes per bin (bin fits one LDS stage)
#define NBIN_MAX 1024         // N <= 1024*256 = 262144 (and N < 2^18 gate)
#define SCAP 10880            // LDS staging capacity (records); mean bin = 8192

typedef unsigned uvec4 __attribute__((ext_vector_type(4)));
struct rec12 { unsigned x, y, z; };   // 12B packed payload
union U32H2 { unsigned u; __half2 h; };

__device__ __forceinline__ float tanh_fast(float x) {
    float e = __expf(2.0f * x);
    float r = __builtin_amdgcn_rcpf(1.0f + e);
    return 1.0f - 2.0f * r;
}

__device__ __forceinline__ float softplus_f(float x) {
    return fmaxf(x, 0.0f) + log1pf(expf(-fabsf(x)));
}

// ===================== prep =====================

// coords4[n] = {x, y, z, g1=|x|+|y|+|z|}: g1 rides along with every cf gather.
__global__ __launch_bounds__(256) void coords4_kernel(
    const float* __restrict__ coords, float4* __restrict__ coords4, int N)
{
    int n = blockIdx.x * blockDim.x + threadIdx.x;
    if (n >= N) return;
    float4 c;
    c.x = coords[n * 3 + 0];
    c.y = coords[n * 3 + 1];
    c.z = coords[n * 3 + 2];
    c.w = fabsf(c.x) + fabsf(c.y) + fabsf(c.z);
    coords4[n] = c;
}

// ===================== build: 2-pass radix with full nt-sort =====================
// Frontier invariant: partial 128B write lines alive at once must fit L2.
// pass1: 782 targets x <=32 resident blocks/XCD (EB=256) = 3.2MB < 4MB; NT input
// loads keep streams out of L2. pass2: one bin = one LDS stage; sorted output is
// streamed out as FULL lines; the scatter re-scan's working set (32 x 98KB =
// 3.1MB/XCD) is L2-resident after the histogram scan warms it.

// Pass 1: block b splits its chunk [ebeg,eend) by 256-node bin, contiguous emit.
// Record: x = nf | (nt&255)<<18 ; y = h2(elen, ev0) ; z = h2(ev1, ev2).
// Emits s1addr[bin][b] = segment start; sentinel row s1addr[NBIN][b] = chunk end.
__global__ __launch_bounds__(CTHR) void pass1_kernel(
    const float* __restrict__ elen,
    const float* __restrict__ evec,
    const int* __restrict__ nfrom,
    const int* __restrict__ nto,
    unsigned* __restrict__ s1addr,
    rec12* __restrict__ payA,
    int E, int NBIN)
{
    __shared__ unsigned hbin[NBIN_MAX];   // 4 KB
    __shared__ unsigned curbin[NBIN_MAX]; // 4 KB
    int b = blockIdx.x, t = threadIdx.x;
    long long ebeg = (long long)E * b / EB;
    long long eend = (long long)E * (b + 1) / EB;

    hbin[t] = 0;
    __syncthreads();
    for (long long e = ebeg + t; e < eend; e += CTHR)
        atomicAdd(&hbin[((unsigned)__builtin_nontemporal_load(&nto[e])) >> BINB], 1u);
    __syncthreads();
    {   // exclusive scan of hbin -> curbin (1024 lanes)
        unsigned v = hbin[t];
        for (int d = 1; d < NBIN_MAX; d <<= 1) {
            unsigned x = (t >= d) ? hbin[t - d] : 0u;
            __syncthreads();
            hbin[t] += x;
            __syncthreads();
        }
        curbin[t] = (unsigned)ebeg + hbin[t] - v;
    }
    __syncthreads();
    if (t < NBIN) s1addr[(size_t)t * EB + b] = curbin[t];
    if (t == 0)  s1addr[(size_t)NBIN * EB + b] = (unsigned)eend;
    __syncthreads();

    for (long long e = ebeg + t; e < eend; e += CTHR) {
        int nf = __builtin_nontemporal_load(&nfrom[e]);
        int nt = __builtin_nontemporal_load(&nto[e]);
        float l  = __builtin_nontemporal_load(&elen[e]);
        float ex = __builtin_nontemporal_load(&evec[e * 3 + 0]);
        float ey = __builtin_nontemporal_load(&evec[e * 3 + 1]);
        float ez = __builtin_nontemporal_load(&evec[e * 3 + 2]);
        unsigned bin = ((unsigned)nt) >> BINB;
        unsigned pos = atomicAdd(&curbin[bin], 1u);
        U32H2 a, c;
        a.h = __floats2half2_rn(l, ex);
        c.h = __floats2half2_rn(ey, ez);
        rec12 r;
        r.x = (unsigned)nf | (((unsigned)nt & ((1u << BINB) - 1u)) << 18);
        r.y = a.u;
        r.z = c.u;
        payA[pos] = r;
    }
}

// Column sums of s1addr rows -> binsum[q] (q = 0..NBIN). EB==256, 256 thr: 1 each.
__global__ __launch_bounds__(256) void colsum_kernel(
    const unsigned* __restrict__ s1addr, unsigned* __restrict__ binsum)
{
    __shared__ unsigned red[256];
    int q = blockIdx.x, t = threadIdx.x;
    red[t] = s1addr[(size_t)q * EB + t];
    __syncthreads();
    for (int d = 128; d > 0; d >>= 1) {
        if (t < d) red[t] += red[t + d];
        __syncthreads();
    }
    if (t == 0) binsum[q] = red[0];
}

// binstart[q] = binsum[q] - binsum[0]  (since s1addr[0][b] = chunk start).
// Also writes the nodestart sentinel at NBIN<<BINB.
__global__ __launch_bounds__(256) void binstart_kernel(
    const unsigned* __restrict__ binsum, unsigned* __restrict__ binstart,
    unsigned* __restrict__ nodestart, int NBIN, int E)
{
    int t = threadIdx.x;
    unsigned b0 = binsum[0];
    for (int q = t; q <= NBIN; q += 256) binstart[q] = binsum[q] - b0;
    if (t == 0) nodestart[(size_t)NBIN << BINB] = (unsigned)E;
}

// Pass 2: one block per bin (256 nodes). Histogram scan (warms L2) -> key scan ->
// cursors + node CSR. Then ONE staged pass: re-scan the bin (L2-hit), scatter all
// records into the 130KB LDS stage via LDS cursors, barrier, stream LDS -> dst as
// contiguous FULL-LINE writes, computing features during streamout (ct gather is
// nt-sorted -> L1; cf gather hidden by a 2-deep pipeline). Oversized bins
// (statistically never) fall back to direct scatter -- still correct.
__global__ __launch_bounds__(CTHR) void pass2_kernel(
    const unsigned* __restrict__ s1addr,
    const unsigned* __restrict__ binstart,
    const float4* __restrict__ coords4,
    const rec12* __restrict__ src,
    rec12* __restrict__ dst,
    unsigned* __restrict__ nodestart,
    int NBIN)
{
    __shared__ unsigned segst[EB];          // 1 KB
    __shared__ unsigned spref[EB + 1];      // 1 KB
    __shared__ unsigned hist[1 << BINB];    // 1 KB
    __shared__ unsigned cur[1 << BINB];     // 1 KB
    __shared__ rec12 stage[SCAP];           // 130.6 KB
    int q = blockIdx.x, t = threadIdx.x;
    const unsigned KMASK = (1u << BINB) - 1u;

    if (t < EB) {
        unsigned st = s1addr[(size_t)q * EB + t];
        unsigned en = s1addr[(size_t)(q + 1) * EB + t];
        segst[t] = st;
        spref[t] = en - st;
    }
    if (t < (1 << BINB)) hist[t] = 0;
    __syncthreads();
    {   // exclusive scan of the 256 segment lengths
        unsigned v = (t < EB) ? spref[t] : 0u;
        for (int d = 1; d < EB; d <<= 1) {
            unsigned x = (t < EB && t >= d) ? spref[t - d] : 0u;
            __syncthreads();
            if (t < EB) spref[t] += x;
            __syncthreads();
        }
        unsigned incl = (t < EB) ? spref[t] : 0u;
        __syncthreads();
        if (t < EB) spref[t] = incl - v;
        if (t == EB - 1) spref[EB] = incl;
    }
    __syncthreads();
    unsigned len = spref[EB];
    unsigned obase = binstart[q];
    const unsigned* srcw = (const unsigned*)src;

    // histogram scan (reads word0; pulls whole lines -> warms L2 for the re-scan)
    for (unsigned i = t; i < len; i += CTHR) {
        unsigned lo = 0, hi = EB;
#pragma unroll
        for (int s = 0; s < 8; s++) {       // log2(EB)
            unsigned mid = (lo + hi) >> 1;
            if (spref[mid] <= i) lo = mid; else hi = mid;
        }
        unsigned x0 = srcw[(size_t)(segst[lo] + (i - spref[lo])) * 3];
        atomicAdd(&hist[(x0 >> 18) & KMASK], 1u);
    }
    __syncthreads();
    // exclusive scan of 256-key histogram (lanes t < 256)
    {
        unsigned hv = (t < (1 << BINB)) ? hist[t] : 0u;
        for (int d = 1; d < (1 << BINB); d <<= 1) {
            unsigned x = (t < (1 << BINB) && t >= d) ? hist[t - d] : 0u;
            __syncthreads();
            if (t < (1 << BINB)) hist[t] += x;
            __syncthreads();
        }
        if (t < (1 << BINB)) {
            unsigned excl = hist[t] - hv;
            cur[t] = obase + excl;
            nodestart[((size_t)q << BINB) + t] = obase + excl;   // node-level CSR
        }
    }
    __syncthreads();

    if (len <= (unsigned)SCAP) {
        // single staged pass: scatter into LDS (no global partial lines)
        for (unsigned i = t; i < len; i += CTHR) {
            unsigned lo = 0, hi = EB;
#pragma unroll
            for (int s = 0; s < 8; s++) {
                unsigned mid = (lo + hi) >> 1;
                if (spref[mid] <= i) lo = mid; else hi = mid;
            }
            rec12 p = src[segst[lo] + (i - spref[lo])];
            unsigned pos = atomicAdd(&cur[(p.x >> 18) & KMASK], 1u);
            stage[pos - obase] = p;
        }
        __syncthreads();
        // streamout: full-line contiguous writes; features computed here.
        // 2-deep pipeline hides the random cf gather; ct gather is nt-sorted.
        unsigned i = t;
        rec12 p0; float4 cf0;
        if (i < len) {
            p0 = stage[i];
            cf0 = coords4[p0.x & 0x3FFFFu];
        }
        while (i < len) {
            unsigned i1 = i + CTHR;
            rec12 p1 = p0; float4 cf1 = cf0;
            if (i1 < len) {
                p1 = stage[i1];
                cf1 = coords4[p1.x & 0x3FFFFu];
            }
            unsigned key = (p0.x >> 18) & KMASK;
            unsigned nf = p0.x & 0x3FFFFu;
            unsigned nt = ((unsigned)q << BINB) | key;
            float4 ct = coords4[nt];
            U32H2 ya, za;
            ya.u = p0.y; za.u = p0.z;
            float g0 = __low2float(ya.h), ev0 = __high2float(ya.h);
            float ev1 = __low2float(za.h), ev2 = __high2float(za.h);
            float g2 = cf0.x * ct.x + cf0.y * ct.y + cf0.z * ct.z;
            float g3 = cf0.x * ev0 + cf0.y * ev1 + cf0.z * ev2;
            U32H2 oy, oz;
            oy.h = __floats2half2_rn(g0, cf0.w);
            oz.h = __floats2half2_rn(g2, g3);
            rec12 r;
            r.x = nf | ((nt & (BSZ - 1u)) << 18);
            r.y = oy.u;
            r.z = oz.u;
            dst[obase + i] = r;
            i = i1; p0 = p1; cf0 = cf1;
        }
    } else {
        // fallback: direct scatter (correct, partial-line cost; ~never taken)
        for (unsigned i = t; i < len; i += CTHR) {
            unsigned lo = 0, hi = EB;
#pragma unroll
            for (int s = 0; s < 8; s++) {
                unsigned mid = (lo + hi) >> 1;
                if (spref[mid] <= i) lo = mid; else hi = mid;
            }
            rec12 p = src[segst[lo] + (i - spref[lo])];
            unsigned key = (p.x >> 18) & KMASK;
            unsigned pos = atomicAdd(&cur[key], 1u);
            unsigned nf = p.x & 0x3FFFFu;
            unsigned nt = ((unsigned)q << BINB) | key;
            float4 cf = coords4[nf];
            float4 ct = coords4[nt];
            U32H2 ya, za;
            ya.u = p.y; za.u = p.z;
            float g0 = __low2float(ya.h), ev0 = __high2float(ya.h);
            float ev1 = __low2float(za.h), ev2 = __high2float(za.h);
            float g2 = cf.x * ct.x + cf.y * ct.y + cf.z * ct.z;
            float g3 = cf.x * ev0 + cf.y * ev1 + cf.z * ev2;
            U32H2 oy, oz;
            oy.h = __floats2half2_rn(g0, cf.w);
            oz.h = __floats2half2_rn(g2, g3);
            rec12 r;
            r.x = nf | ((nt & (BSZ - 1u)) << 18);
            r.y = oy.u;
            r.z = oz.u;
            dst[pos] = r;
        }
    }
}

// ===================== rounds =====================

// wsth[n][j] = fp16( bm[j] + sum_k state[n][k] * Wm[k][j] ), dense 20B rows (4MB total)
__global__ __launch_bounds__(256) void wstate_kernel(
    const float* __restrict__ state, const float* __restrict__ Wm,
    const float* __restrict__ bm, __half* __restrict__ wsth, int N)
{
    int n = blockIdx.x * blockDim.x + threadIdx.x;
    if (n >= N) return;
    const float2* sp = (const float2*)(state + (size_t)n * SD);
    float s[SD];
#pragma unroll
    for (int h = 0; h < 5; h++) { float2 v = sp[h]; s[2*h] = v.x; s[2*h+1] = v.y; }
    float t[SD];
#pragma unroll
    for (int j = 0; j < SD; j++) t[j] = bm[j];
#pragma unroll
    for (int k = 0; k < SD; k++) {
#pragma unroll
        for (int j = 0; j < SD; j++) t[j] += s[k] * Wm[k * SD + j];
    }
    unsigned* dp = (unsigned*)(wsth + (size_t)n * SD);   // 20B rows, 4B aligned
#pragma unroll
    for (int h = 0; h < 5; h++) {
        U32H2 cv;
        cv.h = __floats2half2_rn(t[2*h], t[2*h+1]);
        dp[h] = cv.u;
    }
}

// Run-accumulating round kernel: BSZ=64 -> grid ~3125, high occupancy. Payload
// FULLY nt-sorted (runs ~32/node) -> LDS atomic only on run change. 12B records.
template <bool FIRST>
__global__ __launch_bounds__(256) void round_run_kernel(
    const unsigned* __restrict__ nodestart,
    const rec12* __restrict__ payload,
    const float* __restrict__ Wm,
    const float* __restrict__ bm,
    const __half* __restrict__ wsth,      // (N,10) dense fp16, incl bias
    const float* __restrict__ state_prev,
    float* __restrict__ state_next,
    int N, int E)
{
    __shared__ float acc[BSZ * SD];       // 2.56 KB
    int k = blockIdx.x;
    for (int i = threadIdx.x; i < BSZ * SD; i += 256) acc[i] = 0.0f;

    int lane = threadIdx.x & 63;
    int wv = threadIdx.x >> 6;            // 0..3
    int grp0 = lane / 10;
    bool active = grp0 < 6;
    int grp = active ? grp0 : 5;
    int j = active ? (lane - grp0 * 10) : (lane - 60);

    float w0 = Wm[10 * SD + j];
    float w1 = Wm[11 * SD + j];
    float w2 = Wm[12 * SD + j];
    float w3 = Wm[13 * SD + j];
    float bb = bm[j];
    __syncthreads();

    unsigned beg = nodestart[(size_t)k << 6];
    unsigned end = nodestart[(size_t)(k + 1) << 6];
    unsigned len = end - beg;
    unsigned Q = (len + 3) >> 2;
    unsigned rbeg = beg + (unsigned)wv * Q;
    unsigned rend = rbeg + Q; if (rend > end) rend = end;
    unsigned eclamp = (unsigned)E - 1u;

    // pipeline preload: payload depth 2, wst depth 1
    unsigned e0 = rbeg + (unsigned)grp;
    rec12 P0 = payload[e0 <= eclamp ? e0 : eclamp];
    unsigned e1 = e0 + 6;
    rec12 P1 = payload[e1 <= eclamp ? e1 : eclamp];
    float T0 = bb, T1 = bb;
    if (!FIRST) T0 = __half2float(wsth[(size_t)(P0.x & 0x3FFFFu) * SD + j]);

    int cur_lnt = -1;
    float accv = 0.0f;

    for (unsigned base = rbeg; base < rend; base += 6) {
        unsigned e2 = base + 12 + (unsigned)grp;
        rec12 P2 = payload[e2 <= eclamp ? e2 : eclamp];
        if (!FIRST) T1 = __half2float(wsth[(size_t)(P1.x & 0x3FFFFu) * SD + j]);
        unsigned e = base + (unsigned)grp;
        if (active && e < rend) {
            int lnt = (int)((P0.x >> 18) & (BSZ - 1));
            U32H2 c01, c23;
            c01.u = P0.y; c23.u = P0.z;
            float g0 = __low2float(c01.h), g1 = __high2float(c01.h);
            float g2 = __low2float(c23.h), g3 = __high2float(c23.h);
            float t = T0 + g0 * w0 + g1 * w1 + g2 * w2 + g3 * w3;
            if (lnt != cur_lnt) {
                if (cur_lnt >= 0) atomicAdd(&acc[cur_lnt * SD + j], accv);
                accv = 0.0f;
                cur_lnt = lnt;
            }
            accv += tanh_fast(t);
        }
        P0 = P1; P1 = P2; T0 = T1;
    }
    if (active && cur_lnt >= 0) atomicAdd(&acc[cur_lnt * SD + j], accv);
    __syncthreads();

    int base_o = k * BSZ * SD;
    int lim = N * SD - base_o;
    for (int i = threadIdx.x; i < BSZ * SD; i += 256) {
        if (i < lim) {
            float v = acc[i];
            if (!FIRST) v += state_prev[base_o + i];
            state_next[base_o + i] = v;
        }
    }
}

// ===================== graph phase =====================

__global__ __launch_bounds__(256) void goff_kernel(
    const int* __restrict__ gidx, unsigned* __restrict__ goff, int N, int G)
{
    int n = blockIdx.x * blockDim.x + threadIdx.x;
    if (n >= N) return;
    int g = gidx[n];
    if (n == 0) {
        for (int q = 0; q <= g; q++) goff[q] = 0;
    } else {
        int gp = gidx[n - 1];
        for (int q = gp + 1; q <= g; q++) goff[q] = (unsigned)n;
    }
    if (n == N - 1) {
        for (int q = g + 1; q <= G; q++) goff[q] = (unsigned)N;
    }
}

// 4-way split per (g,j); one atomic per partial. gstate must be zeroed.
__global__ __launch_bounds__(256) void gsum_kernel(
    const float* __restrict__ state, const unsigned* __restrict__ goff,
    float* __restrict__ gstate, int G)
{
    int tid = blockIdx.x * blockDim.x + threadIdx.x;
    if (tid >= G * SD * 4) return;
    int s = tid & 3;
    int rest = tid >> 2;
    int g = rest / SD;
    int j = rest - g * SD;
    unsigned beg = goff[g], end = goff[g + 1];
    unsigned len = end - beg;
    unsigned b0 = beg + (len * (unsigned)s) / 4u;
    unsigned b1 = beg + (len * (unsigned)(s + 1)) / 4u;
    float a = 0.0f;
    for (unsigned n = b0; n < b1; n++) a += state[(size_t)n * SD + j];
    atomicAdd(&gstate[(size_t)g * SD + j], a);
}

__global__ __launch_bounds__(256) void out_kernel(
    const float* __restrict__ gstate, const float* __restrict__ Wo,
    const float* __restrict__ bo, float* __restrict__ out, int G)
{
    int g = blockIdx.x * blockDim.x + threadIdx.x;
    if (g >= G) return;
    float s[SD];
#pragma unroll
    for (int k = 0; k < SD; k++) s[k] = gstate[(size_t)g * SD + k];
    float ev[4];
#pragma unroll
    for (int c = 0; c < 4; c++) {
        float a = bo[c];
#pragma unroll
        for (int k = 0; k < SD; k++) a += s[k] * Wo[k * 4 + c];
        ev[c] = a;
    }
    out[g * 4 + 0] = ev[0];
    out[g * 4 + 1] = softplus_f(ev[1]);
    out[g * 4 + 2] = softplus_f(ev[2]) + 1.0f;
    out[g * 4 + 3] = softplus_f(ev[3]);
}

// ===================== fallback (atomic path) =====================

template <bool FIRST>
__global__ __launch_bounds__(256) void edge_kernel_fb(
    const float* __restrict__ coords, const float* __restrict__ elen,
    const float* __restrict__ evec, const float* __restrict__ Wm,
    const float* __restrict__ bm, const int* __restrict__ nfrom,
    const int* __restrict__ nto, const float* __restrict__ state_prev,
    float* __restrict__ state_next, int E)
{
    int e = blockIdx.x * blockDim.x + threadIdx.x;
    if (e >= E) return;
    int nf = nfrom[e];
    int nt = nto[e];
    float cf0 = coords[nf*3+0], cf1 = coords[nf*3+1], cf2 = coords[nf*3+2];
    float ct0 = coords[nt*3+0], ct1 = coords[nt*3+1], ct2 = coords[nt*3+2];
    float ev0 = evec[e*3+0], ev1 = evec[e*3+1], ev2 = evec[e*3+2];
    float g0 = elen[e];
    float g1 = fabsf(cf0) + fabsf(cf1) + fabsf(cf2);
    float g2 = cf0*ct0 + cf1*ct1 + cf2*ct2;
    float g3 = cf0*ev0 + cf1*ev1 + cf2*ev2;
    float acc[SD];
#pragma unroll
    for (int j = 0; j < SD; j++) {
        acc[j] = bm[j] + g0*Wm[10*SD+j] + g1*Wm[11*SD+j] + g2*Wm[12*SD+j] + g3*Wm[13*SD+j];
    }
    if (!FIRST) {
        const float2* sp = (const float2*)(state_prev + (size_t)nf * SD);
        float s[SD];
#pragma unroll
        for (int h = 0; h < 5; h++) { float2 v = sp[h]; s[2*h] = v.x; s[2*h+1] = v.y; }
#pragma unroll
        for (int k = 0; k < SD; k++) {
#pragma unroll
            for (int j = 0; j < SD; j++) acc[j] += s[k] * Wm[k*SD+j];
        }
    }
    float* dst = state_next + (size_t)nt * SD;
#pragma unroll
    for (int j = 0; j < SD; j++) atomicAdd(dst + j, tanh_fast(acc[j]));
}

__global__ __launch_bounds__(256) void graph_reduce_fb(
    const float* __restrict__ state, const int* __restrict__ gidx,
    float* __restrict__ gstate, int N)
{
    int n = blockIdx.x * blockDim.x + threadIdx.x;
    if (n >= N) return;
    int g = gidx[n];
    const float2* sp = (const float2*)(state + (size_t)n * SD);
    float* dst = gstate + (size_t)g * SD;
#pragma unroll
    for (int h = 0; h < 5; h++) {
        float2 v = sp[h];
        atomicAdd(dst + 2*h, v.x);
        atomicAdd(dst + 2*h + 1, v.y);
    }
}

// ===================== launch =====================

extern "C" void kernel_launch(void* const* d_in, const int* in_sizes, int n_in,
                              void* d_out, int out_size, void* d_ws, size_t ws_size,
                              hipStream_t stream) {
    const float* coords = (const float*)d_in[0];
    const float* elen   = (const float*)d_in[1];
    const float* evec   = (const float*)d_in[2];
    const float* Wm     = (const float*)d_in[3];
    const float* bm     = (const float*)d_in[4];
    const float* Wo     = (const float*)d_in[5];
    const float* bo     = (const float*)d_in[6];
    const int* nfrom    = (const int*)d_in[7];
    const int* nto      = (const int*)d_in[8];
    const int* gidx     = (const int*)d_in[9];

    const int E = in_sizes[1];
    const int N = in_sizes[9];
    const int G = out_size / 4;

    const int NBIN = (N + (1 << BINB) - 1) >> BINB;   // bins (<= 1024)
    const int NB   = (N + BSZ - 1) / BSZ;             // round buckets (~3125)

    const int BLK = 256;
    const int ng = (N + BLK - 1) / BLK;
    const int gg = (G + BLK - 1) / BLK;

    auto align256 = [](size_t x) { return (x + 255) & ~(size_t)255; };
    const size_t state_bytes = align256((size_t)N * SD * sizeof(float));
    const size_t wst_bytes   = align256((size_t)N * SD * sizeof(__half) + 256);
    const size_t payA_bytes  = align256((size_t)E * sizeof(rec12) + 256);
    const size_t payB_bytes  = align256((size_t)E * sizeof(rec12) + 256);
    const size_t s1a_bytes   = align256((size_t)(NBIN_MAX + 1) * EB * sizeof(unsigned));
    const size_t bsum_bytes  = align256((size_t)(NBIN_MAX + 1) * sizeof(unsigned));
    const size_t nst_bytes   = align256(((size_t)NBIN_MAX * (1 << BINB) + 2) * sizeof(unsigned));
    const size_t goff_bytes  = align256((size_t)(G + 1) * sizeof(unsigned));
    const size_t gst_bytes   = align256((size_t)G * SD * sizeof(float));
    const size_t c4_bytes    = align256((size_t)N * sizeof(float4));

    size_t o = 0;
    char* w = (char*)d_ws;
    float* stateA      = (float*)(w + o);    o += state_bytes;
    float* stateB      = (float*)(w + o);    o += state_bytes;
    __half* wsth       = (__half*)(w + o);   o += wst_bytes;
    rec12* payA        = (rec12*)(w + o);    o += payA_bytes;   // bin-sorted block-major
    rec12* payB        = (rec12*)(w + o);    o += payB_bytes;   // fully nt-sorted
    unsigned* s1addr   = (unsigned*)(w + o); o += s1a_bytes;
    unsigned* binsum   = (unsigned*)(w + o); o += bsum_bytes;
    unsigned* binstart = (unsigned*)(w + o); o += bsum_bytes;
    unsigned* nodestart= (unsigned*)(w + o); o += nst_bytes;
    unsigned* goff     = (unsigned*)(w + o); o += goff_bytes;
    float* gstate      = (float*)(w + o);    o += gst_bytes;
    float4* coords4    = (float4*)(w + o);   o += c4_bytes;

    if (o <= ws_size && NBIN <= NBIN_MAX && N < (1 << 18)) {
        // ---- prep + build ----
        coords4_kernel<<<ng, BLK, 0, stream>>>(coords, coords4, N);
        pass1_kernel<<<EB, CTHR, 0, stream>>>(elen, evec, nfrom, nto,
                                              s1addr, payA, E, NBIN);
        colsum_kernel<<<NBIN + 1, 256, 0, stream>>>(s1addr, binsum);
        binstart_kernel<<<1, 256, 0, stream>>>(binsum, binstart, nodestart, NBIN, E);
        pass2_kernel<<<NBIN, CTHR, 0, stream>>>(s1addr, binstart, coords4,
                                                payA, payB, nodestart, NBIN);
        // ---- rounds (sorted 12B payload, high-occupancy 64-node buckets) ----
        round_run_kernel<true><<<NB, BLK, 0, stream>>>(nodestart, payB, Wm, bm,
                                                       wsth, stateB, stateA, N, E);
        wstate_kernel<<<ng, BLK, 0, stream>>>(stateA, Wm, bm, wsth, N);
        round_run_kernel<false><<<NB, BLK, 0, stream>>>(nodestart, payB, Wm, bm,
                                                        wsth, stateA, stateB, N, E);
        wstate_kernel<<<ng, BLK, 0, stream>>>(stateB, Wm, bm, wsth, N);
        round_run_kernel<false><<<NB, BLK, 0, stream>>>(nodestart, payB, Wm, bm,
                                                        wsth, stateB, stateA, N, E);
        // ---- graph phase ----
        hipMemsetAsync(gstate, 0, (size_t)G * SD * sizeof(float), stream);
        goff_kernel<<<ng, BLK, 0, stream>>>(gidx, goff, N, G);
        gsum_kernel<<<(G * SD * 4 + BLK - 1) / BLK, BLK, 0, stream>>>(stateA, goff, gstate, G);
        out_kernel<<<gg, BLK, 0, stream>>>(gstate, Wo, bo, (float*)d_out, G);
    } else {
        // ---- fallback: atomic path ----
        const int eg = (E + BLK - 1) / BLK;
        float* gstateF = (float*)(w + 2 * state_bytes);
        hipMemsetAsync(stateA, 0, state_bytes, stream);
        hipMemsetAsync(gstateF, 0, (size_t)G * SD * sizeof(float), stream);
        edge_kernel_fb<true><<<eg, BLK, 0, stream>>>(coords, elen, evec, Wm, bm,
                                                     nfrom, nto, stateA, stateA, E);
        hipMemcpyAsync(stateB, stateA, state_bytes, hipMemcpyDeviceToDevice, stream);
        edge_kernel_fb<false><<<eg, BLK, 0, stream>>>(coords, elen, evec, Wm, bm,
                                                      nfrom, nto, stateA, stateB, E);
        hipMemcpyAsync(stateA, stateB, state_bytes, hipMemcpyDeviceToDevice, stream);
        edge_kernel_fb<false><<<eg, BLK, 0, stream>>>(coords, elen, evec, Wm, bm,
                                                      nfrom, nto, stateB, stateA, E);
        graph_reduce_fb<<<ng, BLK, 0, stream>>>(stateA, gidx, gstateF, N);
        out_kernel<<<gg, BLK, 0, stream>>>(gstateF, Wo, bo, (float*)d_out, G);
    }
}